// Round 3
// baseline (457.781 us; speedup 1.0000x reference)
//
#include <hip/hip_runtime.h>
#include <hip/hip_bf16.h>
#include <math.h>

#define D_MODEL 1024
#define NH      16
#define DK      64
#define SEQ     2048
#define BATCH   2

typedef float  f32x4  __attribute__((ext_vector_type(4)));
typedef __bf16 bf16x8 __attribute__((ext_vector_type(8)));
typedef unsigned short ushx4 __attribute__((ext_vector_type(4)));
typedef unsigned short ushx8 __attribute__((ext_vector_type(8)));
typedef unsigned short u16;

__device__ inline u16 f2bf(float f) {
    unsigned int u = __float_as_uint(f);
    u += 0x7FFFu + ((u >> 16) & 1u);   // round-to-nearest-even
    return (u16)(u >> 16);
}

__device__ inline void gload16(const u16* g, u16* l) {
    // direct global->LDS DMA, 16B/lane, dest = wave-uniform base + lane*16
    __builtin_amdgcn_global_load_lds(
        (const __attribute__((address_space(1))) unsigned int*)g,
        (__attribute__((address_space(3))) unsigned int*)l,
        16, 0, 0);
}

// ---------------- RoPE tables: cos/sin [SEQ][DK/2] ----------------
__global__ void rope_tables_kernel(float* __restrict__ cost, float* __restrict__ sint) {
    int i = blockIdx.x * 256 + threadIdx.x;      // 2048*32 = 65536 total
    int pos = i >> 5, k = i & 31;
    float inv = powf(10000.0f, -2.0f * (float)k / 64.0f);
    float ang = (float)pos * inv;
    cost[i] = cosf(ang);
    sint[i] = sinf(ang);
}

// ---------------- fp32 -> bf16 converts ----------------
__global__ void cvt_kernel(const float* __restrict__ in, u16* __restrict__ out) {
    size_t i = ((size_t)blockIdx.x * 256 + threadIdx.x) * 8;
    f32x4 v0 = *(const f32x4*)(in + i);
    f32x4 v1 = *(const f32x4*)(in + i + 4);
    ushx4 o0, o1;
    #pragma unroll
    for (int e = 0; e < 4; e++) { o0[e] = f2bf(v0[e]); o1[e] = f2bf(v1[e]); }
    *(ushx4*)(out + i) = o0;
    *(ushx4*)(out + i + 4) = o1;
}

__global__ void cvtw_kernel(const float* __restrict__ wq, const float* __restrict__ wk,
                            const float* __restrict__ wv, const float* __restrict__ wo,
                            u16* __restrict__ oq, u16* __restrict__ ok,
                            u16* __restrict__ ov, u16* __restrict__ oo) {
    const float* in; u16* out;
    switch (blockIdx.y) {
        case 0: in = wq; out = oq; break;
        case 1: in = wk; out = ok; break;
        case 2: in = wv; out = ov; break;
        default: in = wo; out = oo; break;
    }
    size_t i = ((size_t)blockIdx.x * 256 + threadIdx.x) * 8;
    f32x4 v0 = *(const f32x4*)(in + i);
    f32x4 v1 = *(const f32x4*)(in + i + 4);
    ushx4 o0, o1;
    #pragma unroll
    for (int e = 0; e < 4; e++) { o0[e] = f2bf(v0[e]); o1[e] = f2bf(v1[e]); }
    *(ushx4*)(out + i) = o0;
    *(ushx4*)(out + i + 4) = o1;
}

// ---------------- GEMM: C[m][n] = sum_k A[m][k] * W[n][k], bf16 inputs ----------------
// m97 structure: global_load_lds width=16 staging, pre-swizzled source, 2 barriers/K-step.
// MODE 0: RoPE epilogue, store bf16 [b][h][s][dk]
// MODE 1: store bf16 V^T  [b][h][dk][s]
// MODE 2: store fp32 [m][n]
template<int MODE>
__global__ __launch_bounds__(256) void gemm_kernel(
    const u16* __restrict__ A, const u16* __restrict__ W,
    void* __restrict__ outp, const int* __restrict__ tpos,
    const float* __restrict__ cost, const float* __restrict__ sint)
{
    constexpr int K = 1024;
    __shared__ u16 As[128 * 32];
    __shared__ u16 Bs[128 * 32];

    const int t  = threadIdx.x;
    const int m0 = blockIdx.x * 128, n0 = blockIdx.y * 128;
    const int lane = t & 63, wid = t >> 6;
    const int wm = wid >> 1, wn = wid & 1;       // 2x2 wave grid, 64x64 per wave
    const int lr = lane & 15, lg = lane >> 4;

    // staging geometry: wave w stages rows [w*32, w*32+32) of both tiles,
    // two 16-row gload_lds each. LDS linear; source chunk pre-swizzled (rule 21).
    const int ldrow0 = wid * 32 + (lane >> 2);
    const int ldrow1 = ldrow0 + 16;
    const int lc = lane & 3;
    const u16* Asrc0 = A + (size_t)(m0 + ldrow0) * K + ((lc ^ ((ldrow0 >> 1) & 3)) << 3);
    const u16* Asrc1 = A + (size_t)(m0 + ldrow1) * K + ((lc ^ ((ldrow1 >> 1) & 3)) << 3);
    const u16* Bsrc0 = W + (size_t)(n0 + ldrow0) * K + ((lc ^ ((ldrow0 >> 1) & 3)) << 3);
    const u16* Bsrc1 = W + (size_t)(n0 + ldrow1) * K + ((lc ^ ((ldrow1 >> 1) & 3)) << 3);
    u16* Adst0 = &As[(wid * 32) * 32];
    u16* Adst1 = &As[(wid * 32 + 16) * 32];
    u16* Bdst0 = &Bs[(wid * 32) * 32];
    u16* Bdst1 = &Bs[(wid * 32 + 16) * 32];

    f32x4 acc[4][4];
    #pragma unroll
    for (int i = 0; i < 4; i++)
        #pragma unroll
        for (int j = 0; j < 4; j++) acc[i][j] = 0.0f;

    for (int k0 = 0; k0 < K; k0 += 32) {
        __syncthreads();                 // prev iter's ds_reads done; LDS reusable
        gload16(Asrc0 + k0, Adst0);
        gload16(Asrc1 + k0, Adst1);
        gload16(Bsrc0 + k0, Bdst0);
        gload16(Bsrc1 + k0, Bdst1);
        __syncthreads();                 // drains vmcnt(0) before crossing

        bf16x8 af[4], bfr[4];
        #pragma unroll
        for (int mi = 0; mi < 4; mi++) {
            int row = wm * 64 + mi * 16 + lr;
            af[mi] = *(const bf16x8*)&As[row * 32 + ((lg ^ ((row >> 1) & 3)) << 3)];
        }
        #pragma unroll
        for (int ni = 0; ni < 4; ni++) {
            int row = wn * 64 + ni * 16 + lr;
            bfr[ni] = *(const bf16x8*)&Bs[row * 32 + ((lg ^ ((row >> 1) & 3)) << 3)];
        }
        #pragma unroll
        for (int mi = 0; mi < 4; mi++)
            #pragma unroll
            for (int ni = 0; ni < 4; ni++)
                acc[mi][ni] = __builtin_amdgcn_mfma_f32_16x16x32_bf16(af[mi], bfr[ni], acc[mi][ni], 0, 0, 0);
    }

    #pragma unroll
    for (int mi = 0; mi < 4; mi++)
        #pragma unroll
        for (int ni = 0; ni < 4; ni++) {
            f32x4 v4 = acc[mi][ni];
            #pragma unroll
            for (int r = 0; r < 4; r++) {
                int m = m0 + wm * 64 + mi * 16 + lg * 4 + r;
                int n = n0 + wn * 64 + ni * 16 + lr;
                float v = v4[r];
                if constexpr (MODE == 2) {
                    ((float*)outp)[(size_t)m * D_MODEL + n] = v;
                } else if constexpr (MODE == 1) {
                    int b = m >> 11, s = m & 2047;
                    int h = n >> 6,  d = n & 63;
                    ((u16*)outp)[(((size_t)b * NH + h) * DK + d) * SEQ + s] = f2bf(v);
                } else {
                    float vp = __shfl_xor(v, 1);   // pair partner (n parity == lane parity)
                    int b = m >> 11, s = m & 2047;
                    int h = n >> 6,  d = n & 63;
                    int tp = tpos[s];
                    float c  = cost[tp * 32 + (d >> 1)];
                    float sn = sint[tp * 32 + (d >> 1)];
                    float res = (d & 1) ? (vp * sn + v * c) : (v * c - vp * sn);
                    ((u16*)outp)[(((size_t)b * NH + h) * SEQ + s) * DK + d] = f2bf(res);
                }
            }
        }
}

// ---------------- causal flash attention, split-K across 4 waves ----------------
// Q,K bf16 [b][h][s][dk]; VT bf16 [b][h][dk][s]; out bf16 [b][s][h*dk]
// One block per (bh, qt) item; wave w handles key tiles w, w+4, w+8, ...
// Per-wave online softmax, then LDS merge of (m, l, O) partials.
struct KVt { bf16x8 k[2][2]; bf16x8 v[4]; };

__global__ __launch_bounds__(256, 4) void attn_kernel(
    const u16* __restrict__ Q,
    const u16* __restrict__ Km,
    const u16* __restrict__ VT,
    u16* __restrict__ aout)
{
    __shared__ u16 U[4][2048];     // per-wave: P tile (first 1024) during loop, O partial (bf16, 2048) after
    __shared__ float Mm[4][32], Ll[4][32];
    const int t = threadIdx.x, wid = t >> 6, lane = t & 63;
    const int lr = lane & 15, lg = lane >> 4;
    const int item = 2047 - blockIdx.x;          // heavy (large qt) first
    const int bh = item & 31;
    const int qt = item >> 5;                    // 0..63
    const int q0 = qt * 32;
    const int b = bh >> 4, h = bh & 15;

    const u16* Qb = Q  + (size_t)bh * SEQ * DK;
    const u16* Kb = Km + (size_t)bh * SEQ * DK;
    const u16* Vb = VT + (size_t)bh * DK * SEQ;
    u16* Plw = U[wid];

    bf16x8 aq[2][2];
    #pragma unroll
    for (int g = 0; g < 2; g++)
        #pragma unroll
        for (int h2 = 0; h2 < 2; h2++)
            aq[g][h2] = *(const bf16x8*)&Qb[(q0 + g * 16 + lr) * DK + h2 * 32 + lg * 8];

    float m_run[2][4], l_run[2][4];
    f32x4 acc_o[2][4];
    #pragma unroll
    for (int g = 0; g < 2; g++)
        #pragma unroll
        for (int r = 0; r < 4; r++) { m_run[g][r] = -__builtin_inff(); l_run[g][r] = 0.0f; }
    #pragma unroll
    for (int g = 0; g < 2; g++)
        #pragma unroll
        for (int dg = 0; dg < 4; dg++) acc_o[g][dg] = 0.0f;

    auto loadKV = [&](KVt& kv, int kbase) {
        #pragma unroll
        for (int kg = 0; kg < 2; kg++)
            #pragma unroll
            for (int h2 = 0; h2 < 2; h2++)
                kv.k[kg][h2] = *(const bf16x8*)&Kb[(kbase + kg * 16 + lr) * DK + h2 * 32 + lg * 8];
        #pragma unroll
        for (int dg = 0; dg < 4; dg++)
            kv.v[dg] = *(const bf16x8*)&Vb[(size_t)(dg * 16 + lr) * SEQ + kbase + lg * 8];
    };

    auto tile = [&](const KVt& kv, int kbase) {
        f32x4 sf[2][2];
        #pragma unroll
        for (int g = 0; g < 2; g++)
            #pragma unroll
            for (int kg = 0; kg < 2; kg++) sf[g][kg] = 0.0f;
        __builtin_amdgcn_s_setprio(1);
        #pragma unroll
        for (int g = 0; g < 2; g++)
            #pragma unroll
            for (int kg = 0; kg < 2; kg++) {
                sf[g][kg] = __builtin_amdgcn_mfma_f32_16x16x32_bf16(aq[g][0], kv.k[kg][0], sf[g][kg], 0, 0, 0);
                sf[g][kg] = __builtin_amdgcn_mfma_f32_16x16x32_bf16(aq[g][1], kv.k[kg][1], sf[g][kg], 0, 0, 0);
            }
        __builtin_amdgcn_s_setprio(0);

        #pragma unroll
        for (int g = 0; g < 2; g++) {
            float mt[4], scr[4], ts[4], p0a[4], p1a[4];
            #pragma unroll
            for (int r = 0; r < 4; r++) {
                int q = q0 + g * 16 + lg * 4 + r;
                float s0 = sf[g][0][r] * 0.125f;
                float s1 = sf[g][1][r] * 0.125f;
                if (kbase + lr > q)      s0 = -__builtin_inff();
                if (kbase + 16 + lr > q) s1 = -__builtin_inff();
                p0a[r] = s0; p1a[r] = s1;
                mt[r] = fmaxf(s0, s1);
            }
            #pragma unroll
            for (int off = 1; off < 16; off <<= 1)
                #pragma unroll
                for (int r = 0; r < 4; r++) mt[r] = fmaxf(mt[r], __shfl_xor(mt[r], off));
            #pragma unroll
            for (int r = 0; r < 4; r++) {
                float mn = fmaxf(m_run[g][r], mt[r]);
                scr[r] = __expf(m_run[g][r] - mn);
                m_run[g][r] = mn;
                float p0 = __expf(p0a[r] - mn);
                float p1 = __expf(p1a[r] - mn);
                ts[r] = p0 + p1;
                #pragma unroll
                for (int dg = 0; dg < 4; dg++) acc_o[g][dg][r] *= scr[r];
                int qrow = g * 16 + lg * 4 + r;
                int sz = (qrow >> 1) & 3;
                Plw[qrow * 32 + (((lr >> 3) ^ sz) << 3) + (lr & 7)]       = f2bf(p0);
                Plw[qrow * 32 + (((2 + (lr >> 3)) ^ sz) << 3) + (lr & 7)] = f2bf(p1);
            }
            #pragma unroll
            for (int off = 1; off < 16; off <<= 1)
                #pragma unroll
                for (int r = 0; r < 4; r++) ts[r] += __shfl_xor(ts[r], off);
            #pragma unroll
            for (int r = 0; r < 4; r++) l_run[g][r] = l_run[g][r] * scr[r] + ts[r];
        }

        asm volatile("s_waitcnt lgkmcnt(0)" ::: "memory");
        bf16x8 pa[2];
        #pragma unroll
        for (int g = 0; g < 2; g++) {
            int row = g * 16 + lr;
            pa[g] = *(const bf16x8*)&Plw[row * 32 + ((lg ^ ((row >> 1) & 3)) << 3)];
        }
        __builtin_amdgcn_s_setprio(1);
        #pragma unroll
        for (int g = 0; g < 2; g++)
            #pragma unroll
            for (int dg = 0; dg < 4; dg++)
                acc_o[g][dg] = __builtin_amdgcn_mfma_f32_16x16x32_bf16(pa[g], kv.v[dg], acc_o[g][dg], 0, 0, 0);
        __builtin_amdgcn_s_setprio(0);
    };

    // wave wid handles tiles kt = wid, wid+4, ... < ktiles
    const int ktiles = qt + 1;
    const int nmy = (ktiles > wid) ? (((ktiles - 1 - wid) >> 2) + 1) : 0;
    KVt bufA, bufB;
    if (nmy > 0) loadKV(bufA, wid * 32);
    int i = 0;
    while (i < nmy) {
        if (i + 1 < nmy) loadKV(bufB, (wid + 4 * (i + 1)) * 32);
        tile(bufA, (wid + 4 * i) * 32);
        if (++i >= nmy) break;
        if (i + 1 < nmy) loadKV(bufA, (wid + 4 * (i + 1)) * 32);
        tile(bufB, (wid + 4 * i) * 32);
        ++i;
    }

    // write partials (U[wid] region: P is dead for this wave now)
    #pragma unroll
    for (int g = 0; g < 2; g++)
        #pragma unroll
        for (int r = 0; r < 4; r++) {
            int row = g * 16 + lg * 4 + r;
            if (lr == 0) { Mm[wid][row] = m_run[g][r]; Ll[wid][row] = l_run[g][r]; }
            #pragma unroll
            for (int dg = 0; dg < 4; dg++)
                U[wid][row * 64 + dg * 16 + lr] = f2bf(acc_o[g][dg][r]);
        }
    __syncthreads();

    // merge 4 partials: thread t -> row t>>3, cols (t&7)*8 .. +8
    {
        const int row = t >> 3, c0 = (t & 7) * 8;
        float M = fmaxf(fmaxf(Mm[0][row], Mm[1][row]), fmaxf(Mm[2][row], Mm[3][row]));
        float L = 0.0f;
        float o[8];
        #pragma unroll
        for (int e = 0; e < 8; e++) o[e] = 0.0f;
        #pragma unroll
        for (int w = 0; w < 4; w++) {
            float sc = __expf(Mm[w][row] - M);
            L += sc * Ll[w][row];
            ushx8 ov = *(const ushx8*)&U[w][row * 64 + c0];
            #pragma unroll
            for (int e = 0; e < 8; e++) o[e] += sc * __uint_as_float((unsigned)ov[e] << 16);
        }
        float inv = 1.0f / L;
        ushx8 ob;
        #pragma unroll
        for (int e = 0; e < 8; e++) ob[e] = f2bf(o[e] * inv);
        *(ushx8*)&aout[((size_t)b * SEQ + q0 + row) * D_MODEL + h * DK + c0] = ob;
    }
}

extern "C" void kernel_launch(void* const* d_in, const int* in_sizes, int n_in,
                              void* d_out, int out_size, void* d_ws, size_t ws_size,
                              hipStream_t stream) {
    const float* x    = (const float*)d_in[0];
    const int*   tpos = (const int*)d_in[1];
    const float* Wq   = (const float*)d_in[2];
    const float* Wk   = (const float*)d_in[3];
    const float* Wv   = (const float*)d_in[4];
    const float* Wo   = (const float*)d_in[5];
    float* out = (float*)d_out;

    char* ws = (char*)d_ws;
    float* cost = (float*)ws;                                   // 256 KB
    float* sint = (float*)(ws + (256 << 10));                   // 256 KB
    u16* Qb   = (u16*)(ws + (512 << 10));                       // 8 MB
    u16* Kb   = (u16*)(ws + (512 << 10) + ((size_t)8  << 20));  // 8 MB
    u16* VT   = (u16*)(ws + (512 << 10) + ((size_t)16 << 20));  // 8 MB
    u16* xb   = (u16*)(ws + (512 << 10) + ((size_t)24 << 20));  // 8 MB (reused as attnb)
    u16* Wqb  = (u16*)(ws + (512 << 10) + ((size_t)32 << 20));  // 2 MB
    u16* Wkb  = (u16*)(ws + (512 << 10) + ((size_t)34 << 20));
    u16* Wvb  = (u16*)(ws + (512 << 10) + ((size_t)36 << 20));
    u16* Wob  = (u16*)(ws + (512 << 10) + ((size_t)38 << 20));  // total 40.5 MB
    u16* attnb = xb;   // x no longer needed once Q/K/V GEMMs are done (stream-ordered)

    rope_tables_kernel<<<256, 256, 0, stream>>>(cost, sint);
    cvt_kernel<<<2048, 256, 0, stream>>>(x, xb);
    cvtw_kernel<<<dim3(512, 4), 256, 0, stream>>>(Wq, Wk, Wv, Wo, Wqb, Wkb, Wvb, Wob);

    dim3 g(32, 8);
    gemm_kernel<0><<<g, 256, 0, stream>>>(xb, Wqb, Qb, tpos, cost, sint);
    gemm_kernel<0><<<g, 256, 0, stream>>>(xb, Wkb, Kb, tpos, cost, sint);
    gemm_kernel<1><<<g, 256, 0, stream>>>(xb, Wvb, VT, tpos, cost, sint);

    attn_kernel<<<2048, 256, 0, stream>>>(Qb, Kb, VT, attnb);

    gemm_kernel<2><<<g, 256, 0, stream>>>(attnb, Wob, out, tpos, cost, sint);
}

// Round 4
// 252.781 us; speedup vs baseline: 1.8110x; 1.8110x over previous
//
#include <hip/hip_runtime.h>
#include <hip/hip_bf16.h>
#include <math.h>

#define D_MODEL 1024
#define NH      16
#define DK      64
#define SEQ     2048
#define BATCH   2

typedef float  f32x4  __attribute__((ext_vector_type(4)));
typedef __bf16 bf16x8 __attribute__((ext_vector_type(8)));
typedef unsigned short ushx4 __attribute__((ext_vector_type(4)));
typedef unsigned short ushx8 __attribute__((ext_vector_type(8)));
typedef unsigned short u16;

__device__ inline u16 f2bf(float f) {
    unsigned int u = __float_as_uint(f);
    u += 0x7FFFu + ((u >> 16) & 1u);   // round-to-nearest-even
    return (u16)(u >> 16);
}

__device__ inline void gload16(const u16* g, u16* l) {
    // direct global->LDS DMA, 16B/lane, dest = wave-uniform base + lane*16
    __builtin_amdgcn_global_load_lds(
        (const __attribute__((address_space(1))) unsigned int*)g,
        (__attribute__((address_space(3))) unsigned int*)l,
        16, 0, 0);
}

// ---------------- RoPE tables: cos/sin [SEQ][DK/2] ----------------
__global__ void rope_tables_kernel(float* __restrict__ cost, float* __restrict__ sint) {
    int i = blockIdx.x * 256 + threadIdx.x;      // 2048*32 = 65536 total
    int pos = i >> 5, k = i & 31;
    float inv = powf(10000.0f, -2.0f * (float)k / 64.0f);
    float ang = (float)pos * inv;
    cost[i] = cosf(ang);
    sint[i] = sinf(ang);
}

// ---------------- fp32 -> bf16 converts ----------------
__global__ void cvt_kernel(const float* __restrict__ in, u16* __restrict__ out) {
    size_t i = ((size_t)blockIdx.x * 256 + threadIdx.x) * 8;
    f32x4 v0 = *(const f32x4*)(in + i);
    f32x4 v1 = *(const f32x4*)(in + i + 4);
    ushx4 o0, o1;
    #pragma unroll
    for (int e = 0; e < 4; e++) { o0[e] = f2bf(v0[e]); o1[e] = f2bf(v1[e]); }
    *(ushx4*)(out + i) = o0;
    *(ushx4*)(out + i + 4) = o1;
}

__global__ void cvtw_kernel(const float* __restrict__ wq, const float* __restrict__ wk,
                            const float* __restrict__ wv, const float* __restrict__ wo,
                            u16* __restrict__ oq, u16* __restrict__ ok,
                            u16* __restrict__ ov, u16* __restrict__ oo) {
    const float* in; u16* out;
    switch (blockIdx.y) {
        case 0: in = wq; out = oq; break;
        case 1: in = wk; out = ok; break;
        case 2: in = wv; out = ov; break;
        default: in = wo; out = oo; break;
    }
    size_t i = ((size_t)blockIdx.x * 256 + threadIdx.x) * 8;
    f32x4 v0 = *(const f32x4*)(in + i);
    f32x4 v1 = *(const f32x4*)(in + i + 4);
    ushx4 o0, o1;
    #pragma unroll
    for (int e = 0; e < 4; e++) { o0[e] = f2bf(v0[e]); o1[e] = f2bf(v1[e]); }
    *(ushx4*)(out + i) = o0;
    *(ushx4*)(out + i + 4) = o1;
}

// ---------------- GEMM: C[m][n] = sum_k A[m][k] * W[n][k], bf16 inputs ----------------
// m97 structure: global_load_lds width=16 staging, pre-swizzled source, 2 barriers/K-step.
// MODE 0: RoPE epilogue, store bf16 [b][h][s][dk]
// MODE 1: store bf16 V^T  [b][h][dk][s]
// MODE 2: store fp32 [m][n]
template<int MODE>
__global__ __launch_bounds__(256) void gemm_kernel(
    const u16* __restrict__ A, const u16* __restrict__ W,
    void* __restrict__ outp, const int* __restrict__ tpos,
    const float* __restrict__ cost, const float* __restrict__ sint)
{
    constexpr int K = 1024;
    __shared__ u16 As[128 * 32];
    __shared__ u16 Bs[128 * 32];

    const int t  = threadIdx.x;
    const int m0 = blockIdx.x * 128, n0 = blockIdx.y * 128;
    const int lane = t & 63, wid = t >> 6;
    const int wm = wid >> 1, wn = wid & 1;       // 2x2 wave grid, 64x64 per wave
    const int lr = lane & 15, lg = lane >> 4;

    const int ldrow0 = wid * 32 + (lane >> 2);
    const int ldrow1 = ldrow0 + 16;
    const int lc = lane & 3;
    const u16* Asrc0 = A + (size_t)(m0 + ldrow0) * K + ((lc ^ ((ldrow0 >> 1) & 3)) << 3);
    const u16* Asrc1 = A + (size_t)(m0 + ldrow1) * K + ((lc ^ ((ldrow1 >> 1) & 3)) << 3);
    const u16* Bsrc0 = W + (size_t)(n0 + ldrow0) * K + ((lc ^ ((ldrow0 >> 1) & 3)) << 3);
    const u16* Bsrc1 = W + (size_t)(n0 + ldrow1) * K + ((lc ^ ((ldrow1 >> 1) & 3)) << 3);
    u16* Adst0 = &As[(wid * 32) * 32];
    u16* Adst1 = &As[(wid * 32 + 16) * 32];
    u16* Bdst0 = &Bs[(wid * 32) * 32];
    u16* Bdst1 = &Bs[(wid * 32 + 16) * 32];

    f32x4 acc[4][4];
    #pragma unroll
    for (int i = 0; i < 4; i++)
        #pragma unroll
        for (int j = 0; j < 4; j++) acc[i][j] = 0.0f;

    for (int k0 = 0; k0 < K; k0 += 32) {
        __syncthreads();
        gload16(Asrc0 + k0, Adst0);
        gload16(Asrc1 + k0, Adst1);
        gload16(Bsrc0 + k0, Bdst0);
        gload16(Bsrc1 + k0, Bdst1);
        __syncthreads();

        bf16x8 af[4], bfr[4];
        #pragma unroll
        for (int mi = 0; mi < 4; mi++) {
            int row = wm * 64 + mi * 16 + lr;
            af[mi] = *(const bf16x8*)&As[row * 32 + ((lg ^ ((row >> 1) & 3)) << 3)];
        }
        #pragma unroll
        for (int ni = 0; ni < 4; ni++) {
            int row = wn * 64 + ni * 16 + lr;
            bfr[ni] = *(const bf16x8*)&Bs[row * 32 + ((lg ^ ((row >> 1) & 3)) << 3)];
        }
        #pragma unroll
        for (int mi = 0; mi < 4; mi++)
            #pragma unroll
            for (int ni = 0; ni < 4; ni++)
                acc[mi][ni] = __builtin_amdgcn_mfma_f32_16x16x32_bf16(af[mi], bfr[ni], acc[mi][ni], 0, 0, 0);
    }

    #pragma unroll
    for (int mi = 0; mi < 4; mi++)
        #pragma unroll
        for (int ni = 0; ni < 4; ni++) {
            f32x4 v4 = acc[mi][ni];
            #pragma unroll
            for (int r = 0; r < 4; r++) {
                int m = m0 + wm * 64 + mi * 16 + lg * 4 + r;
                int n = n0 + wn * 64 + ni * 16 + lr;
                float v = v4[r];
                if constexpr (MODE == 2) {
                    ((float*)outp)[(size_t)m * D_MODEL + n] = v;
                } else if constexpr (MODE == 1) {
                    int b = m >> 11, s = m & 2047;
                    int h = n >> 6,  d = n & 63;
                    ((u16*)outp)[(((size_t)b * NH + h) * DK + d) * SEQ + s] = f2bf(v);
                } else {
                    float vp = __shfl_xor(v, 1);   // pair partner (n parity == lane parity)
                    int b = m >> 11, s = m & 2047;
                    int h = n >> 6,  d = n & 63;
                    int tp = tpos[s];
                    float c  = cost[tp * 32 + (d >> 1)];
                    float sn = sint[tp * 32 + (d >> 1)];
                    float res = (d & 1) ? (vp * sn + v * c) : (v * c - vp * sn);
                    ((u16*)outp)[(((size_t)b * NH + h) * SEQ + s) * DK + d] = f2bf(res);
                }
            }
        }
}

// ---------------- causal flash attention ----------------
// Q,K bf16 [b][h][s][dk]; VT bf16 [b][h][dk][s]; out bf16 [b][s][h*dk]
// One wave per (bh, 16-row q-tile): 4096 independent wave-items, grid 1024x4waves.
// Block bx: qt = 127 - bx>>3 (heavy first, all 4 waves same qt -> balanced block),
// bh = (bx&7)*4 + wid  -> XCD x (= bx%8) only touches heads 4x..4x+3 (L2-resident).
// Defer-max online softmax: skip max-reduce + rescale unless a local max grows.
__global__ __launch_bounds__(256, 3) void attn_kernel(
    const u16* __restrict__ Q,
    const u16* __restrict__ Km,
    const u16* __restrict__ VT,
    u16* __restrict__ aout)
{
    __shared__ u16 Pl[4][16 * 32];               // 4 KB, per-wave P tile
    const int t = threadIdx.x, wid = t >> 6, lane = t & 63;
    const int lr = lane & 15, lg = lane >> 4;
    const int bx = blockIdx.x;
    const int bh = (bx & 7) * 4 + wid;
    const int qt16 = 127 - (bx >> 3);            // 0..127
    const int q0 = qt16 * 16;
    const int b = bh >> 4, h = bh & 15;
    const int nkt = (qt16 >> 1) + 1;             // 32-key tiles

    const u16* Qb = Q  + (size_t)bh * SEQ * DK;
    const u16* Kb = Km + (size_t)bh * SEQ * DK;
    const u16* Vb = VT + (size_t)bh * DK * SEQ;
    u16* Plw = Pl[wid];

    bf16x8 aq[2];
    aq[0] = *(const bf16x8*)&Qb[(q0 + lr) * DK + lg * 8];
    aq[1] = *(const bf16x8*)&Qb[(q0 + lr) * DK + 32 + lg * 8];

    float m_run[4], l_run[4];
    f32x4 acc[4];
    #pragma unroll
    for (int r = 0; r < 4; r++) { m_run[r] = -__builtin_inff(); l_run[r] = 0.0f; }
    #pragma unroll
    for (int dg = 0; dg < 4; dg++) acc[dg] = 0.0f;

    bf16x8 kf0[2][2], kf1[2][2], vf[4];

    auto loadK = [&](bf16x8 (&kf)[2][2], int kbase) {
        #pragma unroll
        for (int kg = 0; kg < 2; kg++)
            #pragma unroll
            for (int h2 = 0; h2 < 2; h2++)
                kf[kg][h2] = *(const bf16x8*)&Kb[(kbase + kg * 16 + lr) * DK + h2 * 32 + lg * 8];
    };
    auto loadV = [&](int kbase) {
        #pragma unroll
        for (int dg = 0; dg < 4; dg++)
            vf[dg] = *(const bf16x8*)&Vb[(size_t)(dg * 16 + lr) * SEQ + kbase + lg * 8];
    };
    auto qkt = [&](bf16x8 (&kf)[2][2], f32x4 (&sf)[2]) {
        sf[0] = 0.0f; sf[1] = 0.0f;
        __builtin_amdgcn_s_setprio(1);
        #pragma unroll
        for (int kg = 0; kg < 2; kg++) {
            sf[kg] = __builtin_amdgcn_mfma_f32_16x16x32_bf16(aq[0], kf[kg][0], sf[kg], 0, 0, 0);
            sf[kg] = __builtin_amdgcn_mfma_f32_16x16x32_bf16(aq[1], kf[kg][1], sf[kg], 0, 0, 0);
        }
        __builtin_amdgcn_s_setprio(0);
    };

    auto softmax_pv = [&](f32x4 (&sf)[2], int kbase, bool last) {
        float s0[4], s1[4];
        #pragma unroll
        for (int r = 0; r < 4; r++) { s0[r] = sf[0][r] * 0.125f; s1[r] = sf[1][r] * 0.125f; }
        if (last) {
            #pragma unroll
            for (int r = 0; r < 4; r++) {
                int q = q0 + lg * 4 + r;
                if (kbase + lr > q)      s0[r] = -__builtin_inff();
                if (kbase + 16 + lr > q) s1[r] = -__builtin_inff();
            }
        }
        float cmax[4];
        #pragma unroll
        for (int r = 0; r < 4; r++) cmax[r] = fmaxf(s0[r], s1[r]);
        bool ok = (cmax[0] <= m_run[0] + 8.0f) & (cmax[1] <= m_run[1] + 8.0f)
                & (cmax[2] <= m_run[2] + 8.0f) & (cmax[3] <= m_run[3] + 8.0f);
        if (!__all(ok)) {
            float mt[4];
            #pragma unroll
            for (int r = 0; r < 4; r++) mt[r] = cmax[r];
            #pragma unroll
            for (int off = 1; off < 16; off <<= 1)
                #pragma unroll
                for (int r = 0; r < 4; r++) mt[r] = fmaxf(mt[r], __shfl_xor(mt[r], off));
            #pragma unroll
            for (int r = 0; r < 4; r++) {
                float mn = fmaxf(m_run[r], mt[r]);
                float scr = __expf(m_run[r] - mn);
                m_run[r] = mn;
                l_run[r] *= scr;
                #pragma unroll
                for (int dg = 0; dg < 4; dg++) acc[dg][r] *= scr;
            }
        }
        #pragma unroll
        for (int r = 0; r < 4; r++) {
            float p0 = __expf(s0[r] - m_run[r]);
            float p1 = __expf(s1[r] - m_run[r]);
            l_run[r] += p0 + p1;                 // per-lane partial; reduced once at the end
            int qrow = lg * 4 + r;
            int sz = (qrow >> 1) & 3;
            Plw[qrow * 32 + (((lr >> 3) ^ sz) << 3) + (lr & 7)]       = f2bf(p0);
            Plw[qrow * 32 + ((((lr >> 3) + 2) ^ sz) << 3) + (lr & 7)] = f2bf(p1);
        }
        asm volatile("s_waitcnt lgkmcnt(0)" ::: "memory");
        bf16x8 pa = *(const bf16x8*)&Plw[lr * 32 + ((lg ^ ((lr >> 1) & 3)) << 3)];
        __builtin_amdgcn_s_setprio(1);
        #pragma unroll
        for (int dg = 0; dg < 4; dg++)
            acc[dg] = __builtin_amdgcn_mfma_f32_16x16x32_bf16(pa, vf[dg], acc[dg], 0, 0, 0);
        __builtin_amdgcn_s_setprio(0);
    };

    loadK(kf0, 0);
    int kt = 0;
    for (;;) {
        loadV(kt * 32);
        f32x4 sf[2];
        qkt(kf0, sf);
        if (kt + 1 < nkt) loadK(kf1, (kt + 1) * 32);
        softmax_pv(sf, kt * 32, kt == nkt - 1);
        if (++kt >= nkt) break;
        loadV(kt * 32);
        qkt(kf1, sf);
        if (kt + 1 < nkt) loadK(kf0, (kt + 1) * 32);
        softmax_pv(sf, kt * 32, kt == nkt - 1);
        if (++kt >= nkt) break;
    }

    #pragma unroll
    for (int off = 1; off < 16; off <<= 1)
        #pragma unroll
        for (int r = 0; r < 4; r++) l_run[r] += __shfl_xor(l_run[r], off);

    #pragma unroll
    for (int r = 0; r < 4; r++) {
        float inv = 1.0f / l_run[r];
        int q = q0 + lg * 4 + r;
        #pragma unroll
        for (int dg = 0; dg < 4; dg++)
            aout[((size_t)b * SEQ + q) * D_MODEL + h * DK + dg * 16 + lr] = f2bf(acc[dg][r] * inv);
    }
}

extern "C" void kernel_launch(void* const* d_in, const int* in_sizes, int n_in,
                              void* d_out, int out_size, void* d_ws, size_t ws_size,
                              hipStream_t stream) {
    const float* x    = (const float*)d_in[0];
    const int*   tpos = (const int*)d_in[1];
    const float* Wq   = (const float*)d_in[2];
    const float* Wk   = (const float*)d_in[3];
    const float* Wv   = (const float*)d_in[4];
    const float* Wo   = (const float*)d_in[5];
    float* out = (float*)d_out;

    char* ws = (char*)d_ws;
    float* cost = (float*)ws;                                   // 256 KB
    float* sint = (float*)(ws + (256 << 10));                   // 256 KB
    u16* Qb   = (u16*)(ws + (512 << 10));                       // 8 MB
    u16* Kb   = (u16*)(ws + (512 << 10) + ((size_t)8  << 20));  // 8 MB
    u16* VT   = (u16*)(ws + (512 << 10) + ((size_t)16 << 20));  // 8 MB
    u16* xb   = (u16*)(ws + (512 << 10) + ((size_t)24 << 20));  // 8 MB (reused as attnb)
    u16* Wqb  = (u16*)(ws + (512 << 10) + ((size_t)32 << 20));  // 2 MB
    u16* Wkb  = (u16*)(ws + (512 << 10) + ((size_t)34 << 20));
    u16* Wvb  = (u16*)(ws + (512 << 10) + ((size_t)36 << 20));
    u16* Wob  = (u16*)(ws + (512 << 10) + ((size_t)38 << 20));  // total 40.5 MB
    u16* attnb = xb;   // x no longer needed once Q/K/V GEMMs are done (stream-ordered)

    rope_tables_kernel<<<256, 256, 0, stream>>>(cost, sint);
    cvt_kernel<<<2048, 256, 0, stream>>>(x, xb);
    cvtw_kernel<<<dim3(512, 4), 256, 0, stream>>>(Wq, Wk, Wv, Wo, Wqb, Wkb, Wvb, Wob);

    dim3 g(32, 8);
    gemm_kernel<0><<<g, 256, 0, stream>>>(xb, Wqb, Qb, tpos, cost, sint);
    gemm_kernel<0><<<g, 256, 0, stream>>>(xb, Wkb, Kb, tpos, cost, sint);
    gemm_kernel<1><<<g, 256, 0, stream>>>(xb, Wvb, VT, tpos, cost, sint);

    attn_kernel<<<1024, 256, 0, stream>>>(Qb, Kb, VT, attnb);

    gemm_kernel<2><<<g, 256, 0, stream>>>(attnb, Wob, out, tpos, cost, sint);
}

// Round 5
// 157.467 us; speedup vs baseline: 2.9072x; 1.6053x over previous
//
#include <hip/hip_runtime.h>
#include <hip/hip_bf16.h>
#include <math.h>

#define D_MODEL 1024
#define NH      16
#define DK      64
#define SEQ     2048
#define BATCH   2

typedef float  f32x4  __attribute__((ext_vector_type(4)));
typedef __bf16 bf16x8 __attribute__((ext_vector_type(8)));
typedef unsigned short ushx4 __attribute__((ext_vector_type(4)));
typedef unsigned short ushx8 __attribute__((ext_vector_type(8)));
typedef unsigned short u16;

__device__ inline u16 f2bf(float f) {
    unsigned int u = __float_as_uint(f);
    u += 0x7FFFu + ((u >> 16) & 1u);   // round-to-nearest-even
    return (u16)(u >> 16);
}

__device__ inline void gload16(const u16* g, u16* l) {
    // direct global->LDS DMA, 16B/lane, dest = wave-uniform base + lane*16
    __builtin_amdgcn_global_load_lds(
        (const __attribute__((address_space(1))) unsigned int*)g,
        (__attribute__((address_space(3))) unsigned int*)l,
        16, 0, 0);
}

// ---------------- RoPE tables: cos/sin [SEQ][DK/2] ----------------
__global__ void rope_tables_kernel(float* __restrict__ cost, float* __restrict__ sint) {
    int i = blockIdx.x * 256 + threadIdx.x;      // 2048*32 = 65536 total
    int pos = i >> 5, k = i & 31;
    float inv = powf(10000.0f, -2.0f * (float)k / 64.0f);
    float ang = (float)pos * inv;
    cost[i] = cosf(ang);
    sint[i] = sinf(ang);
}

// ---------------- fp32 -> bf16 converts ----------------
__global__ void cvt_kernel(const float* __restrict__ in, u16* __restrict__ out) {
    size_t i = ((size_t)blockIdx.x * 256 + threadIdx.x) * 8;
    f32x4 v0 = *(const f32x4*)(in + i);
    f32x4 v1 = *(const f32x4*)(in + i + 4);
    ushx4 o0, o1;
    #pragma unroll
    for (int e = 0; e < 4; e++) { o0[e] = f2bf(v0[e]); o1[e] = f2bf(v1[e]); }
    *(ushx4*)(out + i) = o0;
    *(ushx4*)(out + i + 4) = o1;
}

__global__ void cvtw_kernel(const float* __restrict__ wq, const float* __restrict__ wk,
                            const float* __restrict__ wv, const float* __restrict__ wo,
                            u16* __restrict__ oq, u16* __restrict__ ok,
                            u16* __restrict__ ov, u16* __restrict__ oo) {
    const float* in; u16* out;
    switch (blockIdx.y) {
        case 0: in = wq; out = oq; break;
        case 1: in = wk; out = ok; break;
        case 2: in = wv; out = ov; break;
        default: in = wo; out = oo; break;
    }
    size_t i = ((size_t)blockIdx.x * 256 + threadIdx.x) * 8;
    f32x4 v0 = *(const f32x4*)(in + i);
    f32x4 v1 = *(const f32x4*)(in + i + 4);
    ushx4 o0, o1;
    #pragma unroll
    for (int e = 0; e < 4; e++) { o0[e] = f2bf(v0[e]); o1[e] = f2bf(v1[e]); }
    *(ushx4*)(out + i) = o0;
    *(ushx4*)(out + i + 4) = o1;
}

// ---------------- fused QKV GEMM: [4096 x 3072] = xb[4096x1024] * Wqkv^T ----------------
// n0 < 1024: RoPE -> Qb; n0 < 2048: RoPE -> Kb; else V^T -> VT
__global__ __launch_bounds__(256) void gemm_qkv(
    const u16* __restrict__ A, const u16* __restrict__ Wqkv,
    u16* __restrict__ Qo, u16* __restrict__ Ko, u16* __restrict__ Vo,
    const int* __restrict__ tpos,
    const float* __restrict__ cost, const float* __restrict__ sint)
{
    constexpr int K = 1024;
    __shared__ u16 As[128 * 32];
    __shared__ u16 Bs[128 * 32];

    const int t  = threadIdx.x;
    const int m0 = blockIdx.x * 128, n0 = blockIdx.y * 128;
    const int lane = t & 63, wid = t >> 6;
    const int wm = wid >> 1, wn = wid & 1;
    const int lr = lane & 15, lg = lane >> 4;

    const int ldrow0 = wid * 32 + (lane >> 2);
    const int ldrow1 = ldrow0 + 16;
    const int lc = lane & 3;
    const u16* Asrc0 = A + (size_t)(m0 + ldrow0) * K + ((lc ^ ((ldrow0 >> 1) & 3)) << 3);
    const u16* Asrc1 = A + (size_t)(m0 + ldrow1) * K + ((lc ^ ((ldrow1 >> 1) & 3)) << 3);
    const u16* Bsrc0 = Wqkv + (size_t)(n0 + ldrow0) * K + ((lc ^ ((ldrow0 >> 1) & 3)) << 3);
    const u16* Bsrc1 = Wqkv + (size_t)(n0 + ldrow1) * K + ((lc ^ ((ldrow1 >> 1) & 3)) << 3);
    u16* Adst0 = &As[(wid * 32) * 32];
    u16* Adst1 = &As[(wid * 32 + 16) * 32];
    u16* Bdst0 = &Bs[(wid * 32) * 32];
    u16* Bdst1 = &Bs[(wid * 32 + 16) * 32];

    f32x4 acc[4][4];
    #pragma unroll
    for (int i = 0; i < 4; i++)
        #pragma unroll
        for (int j = 0; j < 4; j++) acc[i][j] = 0.0f;

    for (int k0 = 0; k0 < K; k0 += 32) {
        __syncthreads();
        gload16(Asrc0 + k0, Adst0);
        gload16(Asrc1 + k0, Adst1);
        gload16(Bsrc0 + k0, Bdst0);
        gload16(Bsrc1 + k0, Bdst1);
        __syncthreads();

        bf16x8 af[4], bfr[4];
        #pragma unroll
        for (int mi = 0; mi < 4; mi++) {
            int row = wm * 64 + mi * 16 + lr;
            af[mi] = *(const bf16x8*)&As[row * 32 + ((lg ^ ((row >> 1) & 3)) << 3)];
        }
        #pragma unroll
        for (int ni = 0; ni < 4; ni++) {
            int row = wn * 64 + ni * 16 + lr;
            bfr[ni] = *(const bf16x8*)&Bs[row * 32 + ((lg ^ ((row >> 1) & 3)) << 3)];
        }
        #pragma unroll
        for (int mi = 0; mi < 4; mi++)
            #pragma unroll
            for (int ni = 0; ni < 4; ni++)
                acc[mi][ni] = __builtin_amdgcn_mfma_f32_16x16x32_bf16(af[mi], bfr[ni], acc[mi][ni], 0, 0, 0);
    }

    const int sel = n0 >> 10;   // 0=Q, 1=K, 2=V (block-uniform)
    #pragma unroll
    for (int mi = 0; mi < 4; mi++)
        #pragma unroll
        for (int ni = 0; ni < 4; ni++) {
            f32x4 v4 = acc[mi][ni];
            #pragma unroll
            for (int r = 0; r < 4; r++) {
                int m = m0 + wm * 64 + mi * 16 + lg * 4 + r;
                int n = n0 + wn * 64 + ni * 16 + lr;
                float v = v4[r];
                int b = m >> 11, s = m & 2047;
                int h = (n >> 6) & 15, d = n & 63;
                if (sel == 2) {
                    Vo[(((size_t)b * NH + h) * DK + d) * SEQ + s] = f2bf(v);
                } else {
                    float vp = __shfl_xor(v, 1);   // pair partner (n parity == lane parity)
                    int tp = tpos[s];
                    float c  = cost[tp * 32 + (d >> 1)];
                    float sn = sint[tp * 32 + (d >> 1)];
                    float res = (d & 1) ? (vp * sn + v * c) : (v * c - vp * sn);
                    u16* outp = sel ? Ko : Qo;
                    outp[(((size_t)b * NH + h) * SEQ + s) * DK + d] = f2bf(res);
                }
            }
        }
}

// ---------------- output projection GEMM: fp32 out ----------------
__global__ __launch_bounds__(256) void gemm_out(
    const u16* __restrict__ A, const u16* __restrict__ W, float* __restrict__ outp)
{
    constexpr int K = 1024;
    __shared__ u16 As[128 * 32];
    __shared__ u16 Bs[128 * 32];

    const int t  = threadIdx.x;
    const int m0 = blockIdx.x * 128, n0 = blockIdx.y * 128;
    const int lane = t & 63, wid = t >> 6;
    const int wm = wid >> 1, wn = wid & 1;
    const int lr = lane & 15, lg = lane >> 4;

    const int ldrow0 = wid * 32 + (lane >> 2);
    const int ldrow1 = ldrow0 + 16;
    const int lc = lane & 3;
    const u16* Asrc0 = A + (size_t)(m0 + ldrow0) * K + ((lc ^ ((ldrow0 >> 1) & 3)) << 3);
    const u16* Asrc1 = A + (size_t)(m0 + ldrow1) * K + ((lc ^ ((ldrow1 >> 1) & 3)) << 3);
    const u16* Bsrc0 = W + (size_t)(n0 + ldrow0) * K + ((lc ^ ((ldrow0 >> 1) & 3)) << 3);
    const u16* Bsrc1 = W + (size_t)(n0 + ldrow1) * K + ((lc ^ ((ldrow1 >> 1) & 3)) << 3);
    u16* Adst0 = &As[(wid * 32) * 32];
    u16* Adst1 = &As[(wid * 32 + 16) * 32];
    u16* Bdst0 = &Bs[(wid * 32) * 32];
    u16* Bdst1 = &Bs[(wid * 32 + 16) * 32];

    f32x4 acc[4][4];
    #pragma unroll
    for (int i = 0; i < 4; i++)
        #pragma unroll
        for (int j = 0; j < 4; j++) acc[i][j] = 0.0f;

    for (int k0 = 0; k0 < K; k0 += 32) {
        __syncthreads();
        gload16(Asrc0 + k0, Adst0);
        gload16(Asrc1 + k0, Adst1);
        gload16(Bsrc0 + k0, Bdst0);
        gload16(Bsrc1 + k0, Bdst1);
        __syncthreads();

        bf16x8 af[4], bfr[4];
        #pragma unroll
        for (int mi = 0; mi < 4; mi++) {
            int row = wm * 64 + mi * 16 + lr;
            af[mi] = *(const bf16x8*)&As[row * 32 + ((lg ^ ((row >> 1) & 3)) << 3)];
        }
        #pragma unroll
        for (int ni = 0; ni < 4; ni++) {
            int row = wn * 64 + ni * 16 + lr;
            bfr[ni] = *(const bf16x8*)&Bs[row * 32 + ((lg ^ ((row >> 1) & 3)) << 3)];
        }
        #pragma unroll
        for (int mi = 0; mi < 4; mi++)
            #pragma unroll
            for (int ni = 0; ni < 4; ni++)
                acc[mi][ni] = __builtin_amdgcn_mfma_f32_16x16x32_bf16(af[mi], bfr[ni], acc[mi][ni], 0, 0, 0);
    }

    #pragma unroll
    for (int mi = 0; mi < 4; mi++)
        #pragma unroll
        for (int ni = 0; ni < 4; ni++) {
            f32x4 v4 = acc[mi][ni];
            #pragma unroll
            for (int r = 0; r < 4; r++) {
                int m = m0 + wm * 64 + mi * 16 + lg * 4 + r;
                int n = n0 + wn * 64 + ni * 16 + lr;
                outp[(size_t)m * D_MODEL + n] = v4[r];
            }
        }
}

// ---------------- causal flash attention, LDS-shared K/V ----------------
// Q,K bf16 [b][h][s][dk]; VT bf16 [b][h][dk][s]; out bf16 [b][s][h*dk]
// Block = 128 q-rows of one (b,h): wave w owns rows qw=q0+w*32 (2 groups of 16).
// K/V tile (64 keys) staged in LDS via global_load_lds, double-buffered,
// one __syncthreads per tile (stage t+1 issued right after the barrier).
// Block mapping: CU pairing makes per-CU tile count constant (36); 4 heads/XCD.
__global__ __launch_bounds__(256) void attn_kernel(
    const u16* __restrict__ Q,
    const u16* __restrict__ Km,
    const u16* __restrict__ VT,
    u16* __restrict__ aout)
{
    __shared__ u16 Ks[2][64 * 64];   // [key][dk], 8B chunks XOR-swizzled by (key&7)
    __shared__ u16 Vs[2][64 * 64];   // [dk][key], 8B chunks XOR-swizzled by (dk&7)
    __shared__ u16 Pl[4][32 * 64];   // per-wave P tile [qrow][key], swizzled by (qrow&7)
    const int t = threadIdx.x, wid = t >> 6, lane = t & 63;
    const int lr = lane & 15, lg = lane >> 4;
    const int bx = blockIdx.x;
    const int k5 = bx >> 5, j = bx & 31;
    const int qb = (k5 < 8) ? (15 - k5) : (k5 - 8);   // heavy-first + balanced CU pairs
    const int bh = (j & 7) * 4 + (j >> 3);            // 4 heads per XCD
    const int b = bh >> 4, h = bh & 15;
    const int q0 = qb * 128;
    const int qw = q0 + wid * 32;
    const int nkt = (q0 >> 6) + 2;
    const int srow = lane >> 3, schunk = lane & 7;

    const u16* Qg = Q  + (size_t)bh * SEQ * DK;
    const u16* Kg = Km + (size_t)bh * SEQ * DK;
    const u16* Vg = VT + (size_t)bh * DK * SEQ;
    u16* Plw = Pl[wid];

    bf16x8 aq[2][2];
    #pragma unroll
    for (int g = 0; g < 2; g++)
        #pragma unroll
        for (int h2 = 0; h2 < 2; h2++)
            aq[g][h2] = *(const bf16x8*)&Qg[(qw + g * 16 + lr) * DK + h2 * 32 + lg * 8];

    float m_run[2][4], l_run[2][4];
    f32x4 acc[2][4];
    #pragma unroll
    for (int g = 0; g < 2; g++)
        #pragma unroll
        for (int r = 0; r < 4; r++) { m_run[g][r] = -__builtin_inff(); l_run[g][r] = 0.0f; }
    #pragma unroll
    for (int g = 0; g < 2; g++)
        #pragma unroll
        for (int dg = 0; dg < 4; dg++) acc[g][dg] = 0.0f;

    // wave stages 16 K rows + 16 V rows per tile; lane l -> row +l/8, chunk l%8.
    // source pre-swizzled: chunk (l%8)^(row&7), row&7 == l/8 here.
    auto stage = [&](int buf, int kb) {
        const int row0 = wid * 16;
        const u16* ks = Kg + (size_t)(kb + row0 + srow) * DK + ((schunk ^ srow) << 3);
        gload16(ks,                 &Ks[buf][row0 * 64]);
        gload16(ks + 8 * DK,        &Ks[buf][(row0 + 8) * 64]);
        const u16* vs = Vg + (size_t)(row0 + srow) * SEQ + kb + ((schunk ^ srow) << 3);
        gload16(vs,                 &Vs[buf][row0 * 64]);
        gload16(vs + (size_t)8 * SEQ, &Vs[buf][(row0 + 8) * 64]);
    };

    stage(0, 0);
    int buf = 0;
    for (int kt = 0; kt < nkt; kt++) {
        __syncthreads();                              // drains vmcnt: tile kt staged; all reads of buf^1 done
        if (kt + 1 < nkt) stage(buf ^ 1, (kt + 1) * 64);   // in flight during compute
        const int kb = kt * 64;
        if (kb <= qw + 31) {                          // wave-uniform: skip fully-masked tiles
            bf16x8 kf[4][2];
            #pragma unroll
            for (int kg = 0; kg < 4; kg++)
                #pragma unroll
                for (int h2 = 0; h2 < 2; h2++) {
                    int row = kg * 16 + lr;
                    kf[kg][h2] = *(const bf16x8*)&Ks[buf][row * 64 + (((h2 * 4 + lg) ^ (lr & 7)) << 3)];
                }
            f32x4 sf[2][4];
            #pragma unroll
            for (int g = 0; g < 2; g++)
                #pragma unroll
                for (int kg = 0; kg < 4; kg++) sf[g][kg] = 0.0f;
            __builtin_amdgcn_s_setprio(1);
            #pragma unroll
            for (int g = 0; g < 2; g++)
                #pragma unroll
                for (int kg = 0; kg < 4; kg++) {
                    sf[g][kg] = __builtin_amdgcn_mfma_f32_16x16x32_bf16(aq[g][0], kf[kg][0], sf[g][kg], 0, 0, 0);
                    sf[g][kg] = __builtin_amdgcn_mfma_f32_16x16x32_bf16(aq[g][1], kf[kg][1], sf[g][kg], 0, 0, 0);
                }
            __builtin_amdgcn_s_setprio(0);

            #pragma unroll
            for (int g = 0; g < 2; g++) {
                float s[4][4];
                #pragma unroll
                for (int kg = 0; kg < 4; kg++)
                    #pragma unroll
                    for (int r = 0; r < 4; r++) s[kg][r] = sf[g][kg][r] * 0.125f;
                if (kb + 64 > qw + g * 16) {          // diagonal band: mask
                    #pragma unroll
                    for (int kg = 0; kg < 4; kg++)
                        #pragma unroll
                        for (int r = 0; r < 4; r++) {
                            int qq = qw + g * 16 + lg * 4 + r;
                            if (kb + kg * 16 + lr > qq) s[kg][r] = -__builtin_inff();
                        }
                }
                float cmax[4];
                #pragma unroll
                for (int r = 0; r < 4; r++)
                    cmax[r] = fmaxf(fmaxf(s[0][r], s[1][r]), fmaxf(s[2][r], s[3][r]));
                bool ok = (cmax[0] <= m_run[g][0] + 8.0f) & (cmax[1] <= m_run[g][1] + 8.0f)
                        & (cmax[2] <= m_run[g][2] + 8.0f) & (cmax[3] <= m_run[g][3] + 8.0f);
                if (!__all(ok)) {
                    float mt[4];
                    #pragma unroll
                    for (int r = 0; r < 4; r++) mt[r] = cmax[r];
                    #pragma unroll
                    for (int off = 1; off < 16; off <<= 1)
                        #pragma unroll
                        for (int r = 0; r < 4; r++) mt[r] = fmaxf(mt[r], __shfl_xor(mt[r], off));
                    #pragma unroll
                    for (int r = 0; r < 4; r++) {
                        float mn = fmaxf(m_run[g][r], mt[r]);
                        float scr = __expf(m_run[g][r] - mn);
                        m_run[g][r] = mn;
                        l_run[g][r] *= scr;
                        #pragma unroll
                        for (int dg = 0; dg < 4; dg++) acc[g][dg][r] *= scr;
                    }
                }
                #pragma unroll
                for (int kg = 0; kg < 4; kg++)
                    #pragma unroll
                    for (int r = 0; r < 4; r++) {
                        float p = __expf(s[kg][r] - m_run[g][r]);
                        l_run[g][r] += p;             // per-lane partial, reduced at the end
                        int qrow = g * 16 + lg * 4 + r;
                        Plw[qrow * 64 + (((kg * 2 + (lr >> 3)) ^ (qrow & 7)) << 3) + (lr & 7)] = f2bf(p);
                    }
            }

            bf16x8 vf[2][4];
            #pragma unroll
            for (int ck = 0; ck < 2; ck++)
                #pragma unroll
                for (int dg = 0; dg < 4; dg++) {
                    int row = dg * 16 + lr;
                    vf[ck][dg] = *(const bf16x8*)&Vs[buf][row * 64 + (((ck * 4 + lg) ^ (lr & 7)) << 3)];
                }
            asm volatile("s_waitcnt lgkmcnt(0)" ::: "memory");   // P writes visible (same wave)
            bf16x8 pa[2][2];
            #pragma unroll
            for (int ck = 0; ck < 2; ck++)
                #pragma unroll
                for (int g = 0; g < 2; g++)
                    pa[ck][g] = *(const bf16x8*)&Plw[(g * 16 + lr) * 64 + (((ck * 4 + lg) ^ (lr & 7)) << 3)];
            __builtin_amdgcn_s_setprio(1);
            #pragma unroll
            for (int ck = 0; ck < 2; ck++)
                #pragma unroll
                for (int g = 0; g < 2; g++)
                    #pragma unroll
                    for (int dg = 0; dg < 4; dg++)
                        acc[g][dg] = __builtin_amdgcn_mfma_f32_16x16x32_bf16(pa[ck][g], vf[ck][dg], acc[g][dg], 0, 0, 0);
            __builtin_amdgcn_s_setprio(0);
        }
        buf ^= 1;
    }

    #pragma unroll
    for (int off = 1; off < 16; off <<= 1)
        #pragma unroll
        for (int g = 0; g < 2; g++)
            #pragma unroll
            for (int r = 0; r < 4; r++) l_run[g][r] += __shfl_xor(l_run[g][r], off);

    #pragma unroll
    for (int g = 0; g < 2; g++)
        #pragma unroll
        for (int r = 0; r < 4; r++) {
            float inv = 1.0f / l_run[g][r];
            int q = qw + g * 16 + lg * 4 + r;
            #pragma unroll
            for (int dg = 0; dg < 4; dg++)
                aout[((size_t)b * SEQ + q) * D_MODEL + h * DK + dg * 16 + lr] = f2bf(acc[g][dg][r] * inv);
        }
}

extern "C" void kernel_launch(void* const* d_in, const int* in_sizes, int n_in,
                              void* d_out, int out_size, void* d_ws, size_t ws_size,
                              hipStream_t stream) {
    const float* x    = (const float*)d_in[0];
    const int*   tpos = (const int*)d_in[1];
    const float* Wq   = (const float*)d_in[2];
    const float* Wk   = (const float*)d_in[3];
    const float* Wv   = (const float*)d_in[4];
    const float* Wo   = (const float*)d_in[5];
    float* out = (float*)d_out;

    char* ws = (char*)d_ws;
    float* cost = (float*)ws;                                   // 256 KB
    float* sint = (float*)(ws + (256 << 10));                   // 256 KB
    u16* Qb   = (u16*)(ws + (512 << 10));                       // 8 MB
    u16* Kb   = (u16*)(ws + (512 << 10) + ((size_t)8  << 20));  // 8 MB
    u16* VT   = (u16*)(ws + (512 << 10) + ((size_t)16 << 20));  // 8 MB
    u16* xb   = (u16*)(ws + (512 << 10) + ((size_t)24 << 20));  // 8 MB (reused as attnb)
    u16* Wqb  = (u16*)(ws + (512 << 10) + ((size_t)32 << 20));  // 2 MB  -- Wq/Wk/Wv contiguous
    u16* Wkb  = (u16*)(ws + (512 << 10) + ((size_t)34 << 20));
    u16* Wvb  = (u16*)(ws + (512 << 10) + ((size_t)36 << 20));
    u16* Wob  = (u16*)(ws + (512 << 10) + ((size_t)38 << 20));  // total 40.5 MB
    u16* attnb = xb;   // x no longer needed once QKV GEMM is done (stream-ordered)

    rope_tables_kernel<<<256, 256, 0, stream>>>(cost, sint);
    cvt_kernel<<<2048, 256, 0, stream>>>(x, xb);
    cvtw_kernel<<<dim3(512, 4), 256, 0, stream>>>(Wq, Wk, Wv, Wo, Wqb, Wkb, Wvb, Wob);

    gemm_qkv<<<dim3(32, 24), 256, 0, stream>>>(xb, Wqb, Qb, Kb, VT, tpos, cost, sint);

    attn_kernel<<<512, 256, 0, stream>>>(Qb, Kb, VT, attnb);

    gemm_out<<<dim3(32, 8), 256, 0, stream>>>(attnb, Wob, out);
}

// Round 6
// 156.110 us; speedup vs baseline: 2.9324x; 1.0087x over previous
//
#include <hip/hip_runtime.h>
#include <hip/hip_bf16.h>
#include <math.h>

#define D_MODEL 1024
#define NH      16
#define DK      64
#define SEQ     2048
#define BATCH   2

typedef float  f32x4  __attribute__((ext_vector_type(4)));
typedef __bf16 bf16x8 __attribute__((ext_vector_type(8)));
typedef unsigned short ushx4 __attribute__((ext_vector_type(4)));
typedef unsigned short ushx8 __attribute__((ext_vector_type(8)));
typedef unsigned short u16;

// RNE float->bf16 via compiler cast (single v_cvt on gfx950)
__device__ inline u16 cbf(float f) { __bf16 h = (__bf16)f; return *(u16*)&h; }

__device__ inline void gload16(const u16* g, u16* l) {
    // direct global->LDS DMA, 16B/lane, dest = wave-uniform base + lane*16
    __builtin_amdgcn_global_load_lds(
        (const __attribute__((address_space(1))) unsigned int*)g,
        (__attribute__((address_space(3))) unsigned int*)l,
        16, 0, 0);
}

// ---------------- RoPE tables: cos/sin [SEQ][DK/2] ----------------
__global__ void rope_tables_kernel(float* __restrict__ cost, float* __restrict__ sint) {
    int i = blockIdx.x * 256 + threadIdx.x;      // 2048*32 = 65536 total
    int pos = i >> 5, k = i & 31;
    float inv = powf(10000.0f, -2.0f * (float)k / 64.0f);
    float ang = (float)pos * inv;
    cost[i] = cosf(ang);
    sint[i] = sinf(ang);
}

// ---------------- fp32 -> bf16 converts ----------------
__global__ void cvt_kernel(const float* __restrict__ in, u16* __restrict__ out) {
    size_t i = ((size_t)blockIdx.x * 256 + threadIdx.x) * 8;
    f32x4 v0 = *(const f32x4*)(in + i);
    f32x4 v1 = *(const f32x4*)(in + i + 4);
    ushx4 o0, o1;
    #pragma unroll
    for (int e = 0; e < 4; e++) { o0[e] = cbf(v0[e]); o1[e] = cbf(v1[e]); }
    *(ushx4*)(out + i) = o0;
    *(ushx4*)(out + i + 4) = o1;
}

__global__ void cvtw_kernel(const float* __restrict__ wq, const float* __restrict__ wk,
                            const float* __restrict__ wv, const float* __restrict__ wo,
                            u16* __restrict__ oq, u16* __restrict__ ok,
                            u16* __restrict__ ov, u16* __restrict__ oo) {
    const float* in; u16* out;
    switch (blockIdx.y) {
        case 0: in = wq; out = oq; break;
        case 1: in = wk; out = ok; break;
        case 2: in = wv; out = ov; break;
        default: in = wo; out = oo; break;
    }
    size_t i = ((size_t)blockIdx.x * 256 + threadIdx.x) * 8;
    f32x4 v0 = *(const f32x4*)(in + i);
    f32x4 v1 = *(const f32x4*)(in + i + 4);
    ushx4 o0, o1;
    #pragma unroll
    for (int e = 0; e < 4; e++) { o0[e] = cbf(v0[e]); o1[e] = cbf(v1[e]); }
    *(ushx4*)(out + i) = o0;
    *(ushx4*)(out + i + 4) = o1;
}

// ---------------- fused QKV GEMM: [4096 x 3072] = xb[4096x1024] * Wqkv^T ----------------
// n0 < 1024: RoPE -> Qb (pre-scaled by 0.125*log2e); n0 < 2048: RoPE -> Kb; else V^T -> VT
__global__ __launch_bounds__(256) void gemm_qkv(
    const u16* __restrict__ A, const u16* __restrict__ Wqkv,
    u16* __restrict__ Qo, u16* __restrict__ Ko, u16* __restrict__ Vo,
    const int* __restrict__ tpos,
    const float* __restrict__ cost, const float* __restrict__ sint)
{
    constexpr int K = 1024;
    __shared__ u16 As[128 * 32];
    __shared__ u16 Bs[128 * 32];

    const int t  = threadIdx.x;
    const int m0 = blockIdx.x * 128, n0 = blockIdx.y * 128;
    const int lane = t & 63, wid = t >> 6;
    const int wm = wid >> 1, wn = wid & 1;
    const int lr = lane & 15, lg = lane >> 4;

    const int ldrow0 = wid * 32 + (lane >> 2);
    const int ldrow1 = ldrow0 + 16;
    const int lc = lane & 3;
    const u16* Asrc0 = A + (size_t)(m0 + ldrow0) * K + ((lc ^ ((ldrow0 >> 1) & 3)) << 3);
    const u16* Asrc1 = A + (size_t)(m0 + ldrow1) * K + ((lc ^ ((ldrow1 >> 1) & 3)) << 3);
    const u16* Bsrc0 = Wqkv + (size_t)(n0 + ldrow0) * K + ((lc ^ ((ldrow0 >> 1) & 3)) << 3);
    const u16* Bsrc1 = Wqkv + (size_t)(n0 + ldrow1) * K + ((lc ^ ((ldrow1 >> 1) & 3)) << 3);
    u16* Adst0 = &As[(wid * 32) * 32];
    u16* Adst1 = &As[(wid * 32 + 16) * 32];
    u16* Bdst0 = &Bs[(wid * 32) * 32];
    u16* Bdst1 = &Bs[(wid * 32 + 16) * 32];

    f32x4 acc[4][4];
    #pragma unroll
    for (int i = 0; i < 4; i++)
        #pragma unroll
        for (int j = 0; j < 4; j++) acc[i][j] = 0.0f;

    for (int k0 = 0; k0 < K; k0 += 32) {
        __syncthreads();
        gload16(Asrc0 + k0, Adst0);
        gload16(Asrc1 + k0, Adst1);
        gload16(Bsrc0 + k0, Bdst0);
        gload16(Bsrc1 + k0, Bdst1);
        __syncthreads();

        bf16x8 af[4], bfr[4];
        #pragma unroll
        for (int mi = 0; mi < 4; mi++) {
            int row = wm * 64 + mi * 16 + lr;
            af[mi] = *(const bf16x8*)&As[row * 32 + ((lg ^ ((row >> 1) & 3)) << 3)];
        }
        #pragma unroll
        for (int ni = 0; ni < 4; ni++) {
            int row = wn * 64 + ni * 16 + lr;
            bfr[ni] = *(const bf16x8*)&Bs[row * 32 + ((lg ^ ((row >> 1) & 3)) << 3)];
        }
        #pragma unroll
        for (int mi = 0; mi < 4; mi++)
            #pragma unroll
            for (int ni = 0; ni < 4; ni++)
                acc[mi][ni] = __builtin_amdgcn_mfma_f32_16x16x32_bf16(af[mi], bfr[ni], acc[mi][ni], 0, 0, 0);
    }

    const int sel = n0 >> 10;   // 0=Q, 1=K, 2=V (block-uniform)
    #pragma unroll
    for (int mi = 0; mi < 4; mi++)
        #pragma unroll
        for (int ni = 0; ni < 4; ni++) {
            f32x4 v4 = acc[mi][ni];
            #pragma unroll
            for (int r = 0; r < 4; r++) {
                int m = m0 + wm * 64 + mi * 16 + lg * 4 + r;
                int n = n0 + wn * 64 + ni * 16 + lr;
                float v = v4[r];
                int b = m >> 11, s = m & 2047;
                int h = (n >> 6) & 15, d = n & 63;
                if (sel == 2) {
                    Vo[(((size_t)b * NH + h) * DK + d) * SEQ + s] = cbf(v);
                } else {
                    float vp = __shfl_xor(v, 1);   // pair partner (n parity == lane parity)
                    int tp = tpos[s];
                    float c  = cost[tp * 32 + (d >> 1)];
                    float sn = sint[tp * 32 + (d >> 1)];
                    float res = (d & 1) ? (vp * sn + v * c) : (v * c - vp * sn);
                    if (sel == 0) res *= 0.18033688f;   // 0.125 * log2(e): softmax uses exp2
                    u16* outp = sel ? Ko : Qo;
                    outp[(((size_t)b * NH + h) * SEQ + s) * DK + d] = cbf(res);
                }
            }
        }
}

// ---------------- output projection GEMM: fp32 out ----------------
__global__ __launch_bounds__(256) void gemm_out(
    const u16* __restrict__ A, const u16* __restrict__ W, float* __restrict__ outp)
{
    constexpr int K = 1024;
    __shared__ u16 As[128 * 32];
    __shared__ u16 Bs[128 * 32];

    const int t  = threadIdx.x;
    const int m0 = blockIdx.x * 128, n0 = blockIdx.y * 128;
    const int lane = t & 63, wid = t >> 6;
    const int wm = wid >> 1, wn = wid & 1;
    const int lr = lane & 15, lg = lane >> 4;

    const int ldrow0 = wid * 32 + (lane >> 2);
    const int ldrow1 = ldrow0 + 16;
    const int lc = lane & 3;
    const u16* Asrc0 = A + (size_t)(m0 + ldrow0) * K + ((lc ^ ((ldrow0 >> 1) & 3)) << 3);
    const u16* Asrc1 = A + (size_t)(m0 + ldrow1) * K + ((lc ^ ((ldrow1 >> 1) & 3)) << 3);
    const u16* Bsrc0 = W + (size_t)(n0 + ldrow0) * K + ((lc ^ ((ldrow0 >> 1) & 3)) << 3);
    const u16* Bsrc1 = W + (size_t)(n0 + ldrow1) * K + ((lc ^ ((ldrow1 >> 1) & 3)) << 3);
    u16* Adst0 = &As[(wid * 32) * 32];
    u16* Adst1 = &As[(wid * 32 + 16) * 32];
    u16* Bdst0 = &Bs[(wid * 32) * 32];
    u16* Bdst1 = &Bs[(wid * 32 + 16) * 32];

    f32x4 acc[4][4];
    #pragma unroll
    for (int i = 0; i < 4; i++)
        #pragma unroll
        for (int j = 0; j < 4; j++) acc[i][j] = 0.0f;

    for (int k0 = 0; k0 < K; k0 += 32) {
        __syncthreads();
        gload16(Asrc0 + k0, Adst0);
        gload16(Asrc1 + k0, Adst1);
        gload16(Bsrc0 + k0, Bdst0);
        gload16(Bsrc1 + k0, Bdst1);
        __syncthreads();

        bf16x8 af[4], bfr[4];
        #pragma unroll
        for (int mi = 0; mi < 4; mi++) {
            int row = wm * 64 + mi * 16 + lr;
            af[mi] = *(const bf16x8*)&As[row * 32 + ((lg ^ ((row >> 1) & 3)) << 3)];
        }
        #pragma unroll
        for (int ni = 0; ni < 4; ni++) {
            int row = wn * 64 + ni * 16 + lr;
            bfr[ni] = *(const bf16x8*)&Bs[row * 32 + ((lg ^ ((row >> 1) & 3)) << 3)];
        }
        #pragma unroll
        for (int mi = 0; mi < 4; mi++)
            #pragma unroll
            for (int ni = 0; ni < 4; ni++)
                acc[mi][ni] = __builtin_amdgcn_mfma_f32_16x16x32_bf16(af[mi], bfr[ni], acc[mi][ni], 0, 0, 0);
    }

    #pragma unroll
    for (int mi = 0; mi < 4; mi++)
        #pragma unroll
        for (int ni = 0; ni < 4; ni++) {
            f32x4 v4 = acc[mi][ni];
            #pragma unroll
            for (int r = 0; r < 4; r++) {
                int m = m0 + wm * 64 + mi * 16 + lg * 4 + r;
                int n = n0 + wn * 64 + ni * 16 + lr;
                outp[(size_t)m * D_MODEL + n] = v4[r];
            }
        }
}

// ---------------- causal flash attention, swapped-operand softmax ----------------
// Q bf16 [b][h][s][dk] PRE-SCALED by 0.125*log2e; K bf16 [b][h][s][dk]; VT bf16 [b][h][dk][s].
// Block = 128 q-rows of one (b,h); wave w owns rows qw..qw+31 (2 groups of 16).
// S^T = mfma(K, Q): lane owns qrow = lane&15, keys lg*4+r -> packed b64 P-stores,
// 2-shuffle row reductions, per-lane-uniform rescale.
// O^T = mfma(V^T, P^T): C-layout col = qrow = lane&15 -> packed b64 output stores.
__global__ __launch_bounds__(256) void attn_kernel(
    const u16* __restrict__ Q,
    const u16* __restrict__ Km,
    const u16* __restrict__ VT,
    u16* __restrict__ aout)
{
    __shared__ u16 Ks[2][64 * 64];   // [key][dk], 16B chunks XOR-swizzled by (key&7)
    __shared__ u16 Vs[2][64 * 64];   // [dk][key], 16B chunks XOR-swizzled by (dk&7)
    __shared__ u16 Pl[4][32 * 64];   // per-wave P [qrow][key], 8B chunks XOR-swizzled by ((qrow&7)<<1)
    const int t = threadIdx.x, wid = t >> 6, lane = t & 63;
    const int lr = lane & 15, lg = lane >> 4;
    const int bx = blockIdx.x;
    const int k5 = bx >> 5, j = bx & 31;
    const int qb = (k5 < 8) ? (15 - k5) : (k5 - 8);   // heavy-first + balanced CU pairs
    const int bh = (j & 7) * 4 + (j >> 3);            // 4 heads per XCD
    const int b = bh >> 4, h = bh & 15;
    const int q0 = qb * 128;
    const int qw = q0 + wid * 32;
    const int nkt = (q0 >> 6) + 2;
    const int srow = lane >> 3, schunk = lane & 7;

    const u16* Qg = Q  + (size_t)bh * SEQ * DK;
    const u16* Kg = Km + (size_t)bh * SEQ * DK;
    const u16* Vg = VT + (size_t)bh * DK * SEQ;
    u16* Plw = Pl[wid];

    // Q fragments (B-operand): lane holds col qrow = qw+g*16+lr, k-elems dk = h2*32+lg*8..+7
    bf16x8 aq[2][2];
    #pragma unroll
    for (int g = 0; g < 2; g++)
        #pragma unroll
        for (int h2 = 0; h2 < 2; h2++)
            aq[g][h2] = *(const bf16x8*)&Qg[(qw + g * 16 + lr) * DK + h2 * 32 + lg * 8];

    float m_run[2], l_run[2];
    f32x4 acc[2][4];   // acc[g][dg]: O[qrow=qw+g*16+lr][d = dg*16+lg*4+r]
    #pragma unroll
    for (int g = 0; g < 2; g++) { m_run[g] = -__builtin_inff(); l_run[g] = 0.0f; }
    #pragma unroll
    for (int g = 0; g < 2; g++)
        #pragma unroll
        for (int dg = 0; dg < 4; dg++) acc[g][dg] = 0.0f;

    auto stage = [&](int buf, int kb) {
        const int row0 = wid * 16;
        const u16* ks = Kg + (size_t)(kb + row0 + srow) * DK + ((schunk ^ srow) << 3);
        gload16(ks,                   &Ks[buf][row0 * 64]);
        gload16(ks + 8 * DK,          &Ks[buf][(row0 + 8) * 64]);
        const u16* vs = Vg + (size_t)(row0 + srow) * SEQ + kb + ((schunk ^ srow) << 3);
        gload16(vs,                   &Vs[buf][row0 * 64]);
        gload16(vs + (size_t)8 * SEQ, &Vs[buf][(row0 + 8) * 64]);
    };

    stage(0, 0);
    int buf = 0;
    for (int kt = 0; kt < nkt; kt++) {
        __syncthreads();                              // tile kt staged; reads of buf^1 done
        if (kt + 1 < nkt) stage(buf ^ 1, (kt + 1) * 64);
        const int kb = kt * 64;
        if (kb <= qw + 31) {                          // wave-uniform skip of fully-masked tiles
            // K fragments (A-operand): lane holds row key = kg*16+lr
            bf16x8 kf[4][2];
            #pragma unroll
            for (int kg = 0; kg < 4; kg++)
                #pragma unroll
                for (int h2 = 0; h2 < 2; h2++) {
                    int row = kg * 16 + lr;
                    kf[kg][h2] = *(const bf16x8*)&Ks[buf][row * 64 + (((h2 * 4 + lg) ^ (lr & 7)) << 3)];
                }
            // V^T fragments (A-operand): lane holds row d = dg*16+lr, k-elems key = ck*32+lg*8..+7
            bf16x8 vf[2][4];
            #pragma unroll
            for (int ck = 0; ck < 2; ck++)
                #pragma unroll
                for (int dg = 0; dg < 4; dg++) {
                    int row = dg * 16 + lr;
                    vf[ck][dg] = *(const bf16x8*)&Vs[buf][row * 64 + (((ck * 4 + lg) ^ (lr & 7)) << 3)];
                }

            // S^T[key][qrow] = K . Q^T  (lane: qrow = lr, key = kg*16+lg*4+r)
            f32x4 sf[2][4];
            #pragma unroll
            for (int g = 0; g < 2; g++)
                #pragma unroll
                for (int kg = 0; kg < 4; kg++) sf[g][kg] = 0.0f;
            __builtin_amdgcn_s_setprio(1);
            #pragma unroll
            for (int g = 0; g < 2; g++)
                #pragma unroll
                for (int kg = 0; kg < 4; kg++) {
                    sf[g][kg] = __builtin_amdgcn_mfma_f32_16x16x32_bf16(kf[kg][0], aq[g][0], sf[g][kg], 0, 0, 0);
                    sf[g][kg] = __builtin_amdgcn_mfma_f32_16x16x32_bf16(kf[kg][1], aq[g][1], sf[g][kg], 0, 0, 0);
                }
            __builtin_amdgcn_s_setprio(0);

            #pragma unroll
            for (int g = 0; g < 2; g++) {
                if (kb + 64 > qw + g * 16) {          // diagonal band: mask
                    const int qq = qw + g * 16 + lr;
                    #pragma unroll
                    for (int kg = 0; kg < 4; kg++)
                        #pragma unroll
                        for (int r = 0; r < 4; r++)
                            if (kb + kg * 16 + lg * 4 + r > qq) sf[g][kg][r] = -__builtin_inff();
                }
                // in-lane max over this lane's 16 keys
                float cmax = sf[g][0][0];
                #pragma unroll
                for (int kg = 0; kg < 4; kg++)
                    #pragma unroll
                    for (int r = 0; r < 4; r++) cmax = fmaxf(cmax, sf[g][kg][r]);
                if (!__all(cmax <= m_run[g] + 8.0f)) {      // defer-max (log2 units)
                    float mt = fmaxf(cmax, __shfl_xor(cmax, 16));
                    mt = fmaxf(mt, __shfl_xor(mt, 32));
                    float mn = fmaxf(m_run[g], mt);
                    float scr = exp2f(m_run[g] - mn);
                    m_run[g] = mn;
                    l_run[g] *= scr;
                    #pragma unroll
                    for (int dg = 0; dg < 4; dg++) acc[g][dg] *= scr;
                }
                float l = 0.0f;
                const int prow = (g * 16 + lr) * 64;
                #pragma unroll
                for (int kg = 0; kg < 4; kg++) {
                    ushx4 pk;
                    #pragma unroll
                    for (int r = 0; r < 4; r++) {
                        float p = exp2f(sf[g][kg][r] - m_run[g]);
                        l += p;
                        pk[r] = cbf(p);
                    }
                    *(ushx4*)&Plw[prow + (((kg * 4 + lg) ^ ((lr & 7) << 1)) << 2)] = pk;
                }
                l_run[g] += l;                        // per-lane partial (this lane's 16 keys)
            }

            asm volatile("s_waitcnt lgkmcnt(0)" ::: "memory");   // P writes visible (same wave)
            // P^T fragments (B-operand): lane holds col qrow = g*16+lr, k-elems key = ck*32+lg*8..+7
            bf16x8 pa[2][2];
            #pragma unroll
            for (int ck = 0; ck < 2; ck++)
                #pragma unroll
                for (int g = 0; g < 2; g++)
                    pa[ck][g] = *(const bf16x8*)&Plw[(g * 16 + lr) * 64 + (((ck * 8 + lg * 2) ^ ((lr & 7) << 1)) << 2)];
            __builtin_amdgcn_s_setprio(1);
            #pragma unroll
            for (int ck = 0; ck < 2; ck++)
                #pragma unroll
                for (int g = 0; g < 2; g++)
                    #pragma unroll
                    for (int dg = 0; dg < 4; dg++)
                        acc[g][dg] = __builtin_amdgcn_mfma_f32_16x16x32_bf16(vf[ck][dg], pa[ck][g], acc[g][dg], 0, 0, 0);
            __builtin_amdgcn_s_setprio(0);
        }
        buf ^= 1;
    }

    // l partials: sum across the 4 lg lane-groups of each row
    #pragma unroll
    for (int g = 0; g < 2; g++) {
        l_run[g] += __shfl_xor(l_run[g], 16);
        l_run[g] += __shfl_xor(l_run[g], 32);
    }

    #pragma unroll
    for (int g = 0; g < 2; g++) {
        float inv = 1.0f / l_run[g];
        int q = qw + g * 16 + lr;
        #pragma unroll
        for (int dg = 0; dg < 4; dg++) {
            ushx4 ow;
            #pragma unroll
            for (int r = 0; r < 4; r++) ow[r] = cbf(acc[g][dg][r] * inv);
            *(ushx4*)&aout[((size_t)b * SEQ + q) * D_MODEL + h * DK + dg * 16 + lg * 4] = ow;
        }
    }
}

extern "C" void kernel_launch(void* const* d_in, const int* in_sizes, int n_in,
                              void* d_out, int out_size, void* d_ws, size_t ws_size,
                              hipStream_t stream) {
    const float* x    = (const float*)d_in[0];
    const int*   tpos = (const int*)d_in[1];
    const float* Wq   = (const float*)d_in[2];
    const float* Wk   = (const float*)d_in[3];
    const float* Wv   = (const float*)d_in[4];
    const float* Wo   = (const float*)d_in[5];
    float* out = (float*)d_out;

    char* ws = (char*)d_ws;
    float* cost = (float*)ws;                                   // 256 KB
    float* sint = (float*)(ws + (256 << 10));                   // 256 KB
    u16* Qb   = (u16*)(ws + (512 << 10));                       // 8 MB
    u16* Kb   = (u16*)(ws + (512 << 10) + ((size_t)8  << 20));  // 8 MB
    u16* VT   = (u16*)(ws + (512 << 10) + ((size_t)16 << 20));  // 8 MB
    u16* xb   = (u16*)(ws + (512 << 10) + ((size_t)24 << 20));  // 8 MB (reused as attnb)
    u16* Wqb  = (u16*)(ws + (512 << 10) + ((size_t)32 << 20));  // 2 MB  -- Wq/Wk/Wv contiguous
    u16* Wkb  = (u16*)(ws + (512 << 10) + ((size_t)34 << 20));
    u16* Wvb  = (u16*)(ws + (512 << 10) + ((size_t)36 << 20));
    u16* Wob  = (u16*)(ws + (512 << 10) + ((size_t)38 << 20));  // total 40.5 MB
    u16* attnb = xb;   // x no longer needed once QKV GEMM is done (stream-ordered)

    rope_tables_kernel<<<256, 256, 0, stream>>>(cost, sint);
    cvt_kernel<<<2048, 256, 0, stream>>>(x, xb);
    cvtw_kernel<<<dim3(512, 4), 256, 0, stream>>>(Wq, Wk, Wv, Wo, Wqb, Wkb, Wvb, Wob);

    gemm_qkv<<<dim3(32, 24), 256, 0, stream>>>(xb, Wqb, Qb, Kb, VT, tpos, cost, sint);

    attn_kernel<<<512, 256, 0, stream>>>(Qb, Kb, VT, attnb);

    gemm_out<<<dim3(32, 8), 256, 0, stream>>>(attnb, Wob, out);
}

// Round 7
// 155.394 us; speedup vs baseline: 2.9459x; 1.0046x over previous
//
#include <hip/hip_runtime.h>
#include <hip/hip_bf16.h>
#include <math.h>

#define D_MODEL 1024
#define NH      16
#define DK      64
#define SEQ     2048
#define BATCH   2

typedef float  f32x4  __attribute__((ext_vector_type(4)));
typedef __bf16 bf16x8 __attribute__((ext_vector_type(8)));
typedef unsigned short ushx4 __attribute__((ext_vector_type(4)));
typedef unsigned short ushx8 __attribute__((ext_vector_type(8)));
typedef unsigned short u16;

// RNE float->bf16 via compiler cast (single v_cvt on gfx950)
__device__ inline u16 cbf(float f) { __bf16 h = (__bf16)f; return *(u16*)&h; }

__device__ inline void gload16(const u16* g, u16* l) {
    // direct global->LDS DMA, 16B/lane, dest = wave-uniform base + lane*16
    __builtin_amdgcn_global_load_lds(
        (const __attribute__((address_space(1))) unsigned int*)g,
        (__attribute__((address_space(3))) unsigned int*)l,
        16, 0, 0);
}

// ---------------- RoPE tables: cos/sin [SEQ][DK/2] ----------------
__global__ void rope_tables_kernel(float* __restrict__ cost, float* __restrict__ sint) {
    int i = blockIdx.x * 256 + threadIdx.x;      // 2048*32 = 65536 total
    int pos = i >> 5, k = i & 31;
    float inv = powf(10000.0f, -2.0f * (float)k / 64.0f);
    float ang = (float)pos * inv;
    cost[i] = cosf(ang);
    sint[i] = sinf(ang);
}

// ---------------- fp32 -> bf16 converts ----------------
__global__ void cvt_kernel(const float* __restrict__ in, u16* __restrict__ out) {
    size_t i = ((size_t)blockIdx.x * 256 + threadIdx.x) * 8;
    f32x4 v0 = *(const f32x4*)(in + i);
    f32x4 v1 = *(const f32x4*)(in + i + 4);
    ushx4 o0, o1;
    #pragma unroll
    for (int e = 0; e < 4; e++) { o0[e] = cbf(v0[e]); o1[e] = cbf(v1[e]); }
    *(ushx4*)(out + i) = o0;
    *(ushx4*)(out + i + 4) = o1;
}

__global__ void cvtw_kernel(const float* __restrict__ wq, const float* __restrict__ wk,
                            const float* __restrict__ wv, const float* __restrict__ wo,
                            u16* __restrict__ oq, u16* __restrict__ ok,
                            u16* __restrict__ ov, u16* __restrict__ oo) {
    const float* in; u16* out;
    switch (blockIdx.y) {
        case 0: in = wq; out = oq; break;
        case 1: in = wk; out = ok; break;
        case 2: in = wv; out = ov; break;
        default: in = wo; out = oo; break;
    }
    size_t i = ((size_t)blockIdx.x * 256 + threadIdx.x) * 8;
    f32x4 v0 = *(const f32x4*)(in + i);
    f32x4 v1 = *(const f32x4*)(in + i + 4);
    ushx4 o0, o1;
    #pragma unroll
    for (int e = 0; e < 4; e++) { o0[e] = cbf(v0[e]); o1[e] = cbf(v1[e]); }
    *(ushx4*)(out + i) = o0;
    *(ushx4*)(out + i + 4) = o1;
}

// ---------------- fused QKV GEMM: [4096 x 3072] = xb[4096x1024] * Wqkv^T ----------------
// n0 < 1024: RoPE -> Qb (pre-scaled by 0.125*log2e); n0 < 2048: RoPE -> Kb; else V^T -> VT
__global__ __launch_bounds__(256) void gemm_qkv(
    const u16* __restrict__ A, const u16* __restrict__ Wqkv,
    u16* __restrict__ Qo, u16* __restrict__ Ko, u16* __restrict__ Vo,
    const int* __restrict__ tpos,
    const float* __restrict__ cost, const float* __restrict__ sint)
{
    constexpr int K = 1024;
    __shared__ u16 As[128 * 32];
    __shared__ u16 Bs[128 * 32];

    const int t  = threadIdx.x;
    const int m0 = blockIdx.x * 128, n0 = blockIdx.y * 128;
    const int lane = t & 63, wid = t >> 6;
    const int wm = wid >> 1, wn = wid & 1;
    const int lr = lane & 15, lg = lane >> 4;

    const int ldrow0 = wid * 32 + (lane >> 2);
    const int ldrow1 = ldrow0 + 16;
    const int lc = lane & 3;
    const u16* Asrc0 = A + (size_t)(m0 + ldrow0) * K + ((lc ^ ((ldrow0 >> 1) & 3)) << 3);
    const u16* Asrc1 = A + (size_t)(m0 + ldrow1) * K + ((lc ^ ((ldrow1 >> 1) & 3)) << 3);
    const u16* Bsrc0 = Wqkv + (size_t)(n0 + ldrow0) * K + ((lc ^ ((ldrow0 >> 1) & 3)) << 3);
    const u16* Bsrc1 = Wqkv + (size_t)(n0 + ldrow1) * K + ((lc ^ ((ldrow1 >> 1) & 3)) << 3);
    u16* Adst0 = &As[(wid * 32) * 32];
    u16* Adst1 = &As[(wid * 32 + 16) * 32];
    u16* Bdst0 = &Bs[(wid * 32) * 32];
    u16* Bdst1 = &Bs[(wid * 32 + 16) * 32];

    f32x4 acc[4][4];
    #pragma unroll
    for (int i = 0; i < 4; i++)
        #pragma unroll
        for (int j = 0; j < 4; j++) acc[i][j] = 0.0f;

    for (int k0 = 0; k0 < K; k0 += 32) {
        __syncthreads();
        gload16(Asrc0 + k0, Adst0);
        gload16(Asrc1 + k0, Adst1);
        gload16(Bsrc0 + k0, Bdst0);
        gload16(Bsrc1 + k0, Bdst1);
        __syncthreads();

        bf16x8 af[4], bfr[4];
        #pragma unroll
        for (int mi = 0; mi < 4; mi++) {
            int row = wm * 64 + mi * 16 + lr;
            af[mi] = *(const bf16x8*)&As[row * 32 + ((lg ^ ((row >> 1) & 3)) << 3)];
        }
        #pragma unroll
        for (int ni = 0; ni < 4; ni++) {
            int row = wn * 64 + ni * 16 + lr;
            bfr[ni] = *(const bf16x8*)&Bs[row * 32 + ((lg ^ ((row >> 1) & 3)) << 3)];
        }
        #pragma unroll
        for (int mi = 0; mi < 4; mi++)
            #pragma unroll
            for (int ni = 0; ni < 4; ni++)
                acc[mi][ni] = __builtin_amdgcn_mfma_f32_16x16x32_bf16(af[mi], bfr[ni], acc[mi][ni], 0, 0, 0);
    }

    const int sel = n0 >> 10;   // 0=Q, 1=K, 2=V (block-uniform)
    #pragma unroll
    for (int mi = 0; mi < 4; mi++)
        #pragma unroll
        for (int ni = 0; ni < 4; ni++) {
            f32x4 v4 = acc[mi][ni];
            #pragma unroll
            for (int r = 0; r < 4; r++) {
                int m = m0 + wm * 64 + mi * 16 + lg * 4 + r;
                int n = n0 + wn * 64 + ni * 16 + lr;
                float v = v4[r];
                int b = m >> 11, s = m & 2047;
                int h = (n >> 6) & 15, d = n & 63;
                if (sel == 2) {
                    Vo[(((size_t)b * NH + h) * DK + d) * SEQ + s] = cbf(v);
                } else {
                    float vp = __shfl_xor(v, 1);   // pair partner (n parity == lane parity)
                    int tp = tpos[s];
                    float c  = cost[tp * 32 + (d >> 1)];
                    float sn = sint[tp * 32 + (d >> 1)];
                    float res = (d & 1) ? (vp * sn + v * c) : (v * c - vp * sn);
                    if (sel == 0) res *= 0.18033688f;   // 0.125 * log2(e): softmax uses exp2
                    u16* outp = sel ? Ko : Qo;
                    outp[(((size_t)b * NH + h) * SEQ + s) * DK + d] = cbf(res);
                }
            }
        }
}

// ---------------- output projection GEMM: fp32 out ----------------
__global__ __launch_bounds__(256) void gemm_out(
    const u16* __restrict__ A, const u16* __restrict__ W, float* __restrict__ outp)
{
    constexpr int K = 1024;
    __shared__ u16 As[128 * 32];
    __shared__ u16 Bs[128 * 32];

    const int t  = threadIdx.x;
    const int m0 = blockIdx.x * 128, n0 = blockIdx.y * 128;
    const int lane = t & 63, wid = t >> 6;
    const int wm = wid >> 1, wn = wid & 1;
    const int lr = lane & 15, lg = lane >> 4;

    const int ldrow0 = wid * 32 + (lane >> 2);
    const int ldrow1 = ldrow0 + 16;
    const int lc = lane & 3;
    const u16* Asrc0 = A + (size_t)(m0 + ldrow0) * K + ((lc ^ ((ldrow0 >> 1) & 3)) << 3);
    const u16* Asrc1 = A + (size_t)(m0 + ldrow1) * K + ((lc ^ ((ldrow1 >> 1) & 3)) << 3);
    const u16* Bsrc0 = W + (size_t)(n0 + ldrow0) * K + ((lc ^ ((ldrow0 >> 1) & 3)) << 3);
    const u16* Bsrc1 = W + (size_t)(n0 + ldrow1) * K + ((lc ^ ((ldrow1 >> 1) & 3)) << 3);
    u16* Adst0 = &As[(wid * 32) * 32];
    u16* Adst1 = &As[(wid * 32 + 16) * 32];
    u16* Bdst0 = &Bs[(wid * 32) * 32];
    u16* Bdst1 = &Bs[(wid * 32 + 16) * 32];

    f32x4 acc[4][4];
    #pragma unroll
    for (int i = 0; i < 4; i++)
        #pragma unroll
        for (int j = 0; j < 4; j++) acc[i][j] = 0.0f;

    for (int k0 = 0; k0 < K; k0 += 32) {
        __syncthreads();
        gload16(Asrc0 + k0, Adst0);
        gload16(Asrc1 + k0, Adst1);
        gload16(Bsrc0 + k0, Bdst0);
        gload16(Bsrc1 + k0, Bdst1);
        __syncthreads();

        bf16x8 af[4], bfr[4];
        #pragma unroll
        for (int mi = 0; mi < 4; mi++) {
            int row = wm * 64 + mi * 16 + lr;
            af[mi] = *(const bf16x8*)&As[row * 32 + ((lg ^ ((row >> 1) & 3)) << 3)];
        }
        #pragma unroll
        for (int ni = 0; ni < 4; ni++) {
            int row = wn * 64 + ni * 16 + lr;
            bfr[ni] = *(const bf16x8*)&Bs[row * 32 + ((lg ^ ((row >> 1) & 3)) << 3)];
        }
        #pragma unroll
        for (int mi = 0; mi < 4; mi++)
            #pragma unroll
            for (int ni = 0; ni < 4; ni++)
                acc[mi][ni] = __builtin_amdgcn_mfma_f32_16x16x32_bf16(af[mi], bfr[ni], acc[mi][ni], 0, 0, 0);
    }

    #pragma unroll
    for (int mi = 0; mi < 4; mi++)
        #pragma unroll
        for (int ni = 0; ni < 4; ni++) {
            f32x4 v4 = acc[mi][ni];
            #pragma unroll
            for (int r = 0; r < 4; r++) {
                int m = m0 + wm * 64 + mi * 16 + lg * 4 + r;
                int n = n0 + wn * 64 + ni * 16 + lr;
                outp[(size_t)m * D_MODEL + n] = v4[r];
            }
        }
}

// ---------------- causal flash attention, counted-vmcnt pipeline ----------------
// Q bf16 [b][h][s][dk] PRE-SCALED by 0.125*log2e; K bf16 [b][h][s][dk]; VT bf16 [b][h][dk][s].
// Block = 128 q-rows of one (b,h); wave w owns rows qw..qw+31 (2 groups of 16).
// Swapped softmax: S^T = mfma(K, Q), O^T = mfma(V^T, P^T).
// K double-buffered, V single-buffered in LDS (40 KB total -> 4 blocks/CU).
// Raw s_barrier + counted vmcnt: stage V[kt], K[kt+1] after the barrier;
// vmcnt(4) before K reads (drains K[kt]); vmcnt(2) before V reads (drains V[kt]);
// K[kt+1] stays in flight across the next barrier.
__global__ __launch_bounds__(256) void attn_kernel(
    const u16* __restrict__ Q,
    const u16* __restrict__ Km,
    const u16* __restrict__ VT,
    u16* __restrict__ aout)
{
    __shared__ u16 Ks[2][64 * 64];   // [key][dk], 16B chunks XOR-swizzled by (key&7)
    __shared__ u16 Vs[64 * 64];      // [dk][key], 16B chunks XOR-swizzled by (dk&7)
    __shared__ u16 Pl[4][32 * 64];   // per-wave P [qrow][key], 8B chunks XOR-swizzled
    const int t = threadIdx.x, wid = t >> 6, lane = t & 63;
    const int lr = lane & 15, lg = lane >> 4;
    const int bx = blockIdx.x;
    const int j = bx & 31;
    const int qb = 15 - (bx >> 5);                    // descending work: tail = tiny blocks
    const int bh = (j & 7) * 4 + (j >> 3);            // 4 heads per XCD
    const int b = bh >> 4, h = bh & 15;
    const int q0 = qb * 128;
    const int qw = q0 + wid * 32;
    const int nkt = (q0 >> 6) + 2;
    const int srow = lane >> 3, schunk = lane & 7;

    const u16* Qg = Q  + (size_t)bh * SEQ * DK;
    const u16* Kg = Km + (size_t)bh * SEQ * DK;
    const u16* Vg = VT + (size_t)bh * DK * SEQ;
    u16* Plw = Pl[wid];

    // Q fragments (B-operand): lane holds col qrow = qw+g*16+lr, k-elems dk = h2*32+lg*8..+7
    bf16x8 aq[2][2];
    #pragma unroll
    for (int g = 0; g < 2; g++)
        #pragma unroll
        for (int h2 = 0; h2 < 2; h2++)
            aq[g][h2] = *(const bf16x8*)&Qg[(qw + g * 16 + lr) * DK + h2 * 32 + lg * 8];

    float m_run[2], l_run[2];
    f32x4 acc[2][4];   // acc[g][dg]: O[qrow=qw+g*16+lr][d = dg*16+lg*4+r]
    #pragma unroll
    for (int g = 0; g < 2; g++) { m_run[g] = -__builtin_inff(); l_run[g] = 0.0f; }
    #pragma unroll
    for (int g = 0; g < 2; g++)
        #pragma unroll
        for (int dg = 0; dg < 4; dg++) acc[g][dg] = 0.0f;

    auto stageK = [&](int buf, int kb) {              // 2 gloads per wave
        const int row0 = wid * 16;
        const u16* ks = Kg + (size_t)(kb + row0 + srow) * DK + ((schunk ^ srow) << 3);
        gload16(ks,          &Ks[buf][row0 * 64]);
        gload16(ks + 8 * DK, &Ks[buf][(row0 + 8) * 64]);
    };
    auto stageV = [&](int kb) {                       // 2 gloads per wave
        const int row0 = wid * 16;
        const u16* vs = Vg + (size_t)(row0 + srow) * SEQ + kb + ((schunk ^ srow) << 3);
        gload16(vs,                   &Vs[row0 * 64]);
        gload16(vs + (size_t)8 * SEQ, &Vs[(row0 + 8) * 64]);
    };

    stageK(0, 0);
    for (int kt = 0; kt < nkt; kt++) {
        __builtin_amdgcn_sched_barrier(0);
        __builtin_amdgcn_s_barrier();                 // raw: no vmcnt drain
        __builtin_amdgcn_sched_barrier(0);
        stageV(kt * 64);                              // V[kt] -> Vs (consumed late this iter)
        stageK((kt + 1) & 1, (kt + 1 < nkt) ? (kt + 1) * 64 : 0);  // K[kt+1] (redundant on last)
        const int kb = kt * 64;
        if (kb <= qw + 31) {                          // wave-uniform skip of fully-masked tiles
            asm volatile("s_waitcnt vmcnt(4)" ::: "memory");   // K[kt] landed (V[kt],K[kt+1] fly)
            __builtin_amdgcn_sched_barrier(0);
            // K fragments (A-operand): lane holds row key = kg*16+lr
            bf16x8 kf[4][2];
            #pragma unroll
            for (int kg = 0; kg < 4; kg++)
                #pragma unroll
                for (int h2 = 0; h2 < 2; h2++) {
                    int row = kg * 16 + lr;
                    kf[kg][h2] = *(const bf16x8*)&Ks[kt & 1][row * 64 + (((h2 * 4 + lg) ^ (lr & 7)) << 3)];
                }

            // S^T[key][qrow] = K . Q^T  (lane: qrow = lr, key = kg*16+lg*4+r)
            f32x4 sf[2][4];
            #pragma unroll
            for (int g = 0; g < 2; g++)
                #pragma unroll
                for (int kg = 0; kg < 4; kg++) sf[g][kg] = 0.0f;
            __builtin_amdgcn_s_setprio(1);
            #pragma unroll
            for (int g = 0; g < 2; g++)
                #pragma unroll
                for (int kg = 0; kg < 4; kg++) {
                    sf[g][kg] = __builtin_amdgcn_mfma_f32_16x16x32_bf16(kf[kg][0], aq[g][0], sf[g][kg], 0, 0, 0);
                    sf[g][kg] = __builtin_amdgcn_mfma_f32_16x16x32_bf16(kf[kg][1], aq[g][1], sf[g][kg], 0, 0, 0);
                }
            __builtin_amdgcn_s_setprio(0);

            #pragma unroll
            for (int g = 0; g < 2; g++) {
                if (kb + 64 > qw + g * 16) {          // diagonal band: mask
                    const int qq = qw + g * 16 + lr;
                    #pragma unroll
                    for (int kg = 0; kg < 4; kg++)
                        #pragma unroll
                        for (int r = 0; r < 4; r++)
                            if (kb + kg * 16 + lg * 4 + r > qq) sf[g][kg][r] = -__builtin_inff();
                }
                float cmax = sf[g][0][0];
                #pragma unroll
                for (int kg = 0; kg < 4; kg++)
                    #pragma unroll
                    for (int r = 0; r < 4; r++) cmax = fmaxf(cmax, sf[g][kg][r]);
                if (!__all(cmax <= m_run[g] + 8.0f)) {      // defer-max (log2 units)
                    float mt = fmaxf(cmax, __shfl_xor(cmax, 16));
                    mt = fmaxf(mt, __shfl_xor(mt, 32));
                    float mn = fmaxf(m_run[g], mt);
                    float scr = exp2f(m_run[g] - mn);
                    m_run[g] = mn;
                    l_run[g] *= scr;
                    #pragma unroll
                    for (int dg = 0; dg < 4; dg++) acc[g][dg] *= scr;
                }
                float l = 0.0f;
                const int prow = (g * 16 + lr) * 64;
                #pragma unroll
                for (int kg = 0; kg < 4; kg++) {
                    ushx4 pk;
                    #pragma unroll
                    for (int r = 0; r < 4; r++) {
                        float p = exp2f(sf[g][kg][r] - m_run[g]);
                        l += p;
                        pk[r] = cbf(p);
                    }
                    *(ushx4*)&Plw[prow + (((kg * 4 + lg) ^ ((lr & 7) << 1)) << 2)] = pk;
                }
                l_run[g] += l;                        // per-lane partial (this lane's 16 keys)
            }

            asm volatile("s_waitcnt vmcnt(2)" ::: "memory");   // V[kt] landed (K[kt+1] flies)
            __builtin_amdgcn_sched_barrier(0);
            // V^T fragments (A-operand): lane holds row d = dg*16+lr, k-elems key = ck*32+lg*8..+7
            bf16x8 vf[2][4];
            #pragma unroll
            for (int ck = 0; ck < 2; ck++)
                #pragma unroll
                for (int dg = 0; dg < 4; dg++) {
                    int row = dg * 16 + lr;
                    vf[ck][dg] = *(const bf16x8*)&Vs[row * 64 + (((ck * 4 + lg) ^ (lr & 7)) << 3)];
                }

            asm volatile("s_waitcnt lgkmcnt(0)" ::: "memory");   // P writes done (same-wave DS order)
            __builtin_amdgcn_sched_barrier(0);
            // P^T fragments (B-operand): lane holds col qrow = g*16+lr, k-elems key = ck*32+lg*8..+7
            bf16x8 pa[2][2];
            #pragma unroll
            for (int ck = 0; ck < 2; ck++)
                #pragma unroll
                for (int g = 0; g < 2; g++)
                    pa[ck][g] = *(const bf16x8*)&Plw[(g * 16 + lr) * 64 + (((ck * 8 + lg * 2) ^ ((lr & 7) << 1)) << 2)];
            __builtin_amdgcn_s_setprio(1);
            #pragma unroll
            for (int ck = 0; ck < 2; ck++)
                #pragma unroll
                for (int g = 0; g < 2; g++)
                    #pragma unroll
                    for (int dg = 0; dg < 4; dg++)
                        acc[g][dg] = __builtin_amdgcn_mfma_f32_16x16x32_bf16(vf[ck][dg], pa[ck][g], acc[g][dg], 0, 0, 0);
            __builtin_amdgcn_s_setprio(0);
        }
    }

    // l partials: sum across the 4 lg lane-groups of each row
    #pragma unroll
    for (int g = 0; g < 2; g++) {
        l_run[g] += __shfl_xor(l_run[g], 16);
        l_run[g] += __shfl_xor(l_run[g], 32);
    }

    #pragma unroll
    for (int g = 0; g < 2; g++) {
        float inv = 1.0f / l_run[g];
        int q = qw + g * 16 + lr;
        #pragma unroll
        for (int dg = 0; dg < 4; dg++) {
            ushx4 ow;
            #pragma unroll
            for (int r = 0; r < 4; r++) ow[r] = cbf(acc[g][dg][r] * inv);
            *(ushx4*)&aout[((size_t)b * SEQ + q) * D_MODEL + h * DK + dg * 16 + lg * 4] = ow;
        }
    }
}

extern "C" void kernel_launch(void* const* d_in, const int* in_sizes, int n_in,
                              void* d_out, int out_size, void* d_ws, size_t ws_size,
                              hipStream_t stream) {
    const float* x    = (const float*)d_in[0];
    const int*   tpos = (const int*)d_in[1];
    const float* Wq   = (const float*)d_in[2];
    const float* Wk   = (const float*)d_in[3];
    const float* Wv   = (const float*)d_in[4];
    const float* Wo   = (const float*)d_in[5];
    float* out = (float*)d_out;

    char* ws = (char*)d_ws;
    float* cost = (float*)ws;                                   // 256 KB
    float* sint = (float*)(ws + (256 << 10));                   // 256 KB
    u16* Qb   = (u16*)(ws + (512 << 10));                       // 8 MB
    u16* Kb   = (u16*)(ws + (512 << 10) + ((size_t)8  << 20));  // 8 MB
    u16* VT   = (u16*)(ws + (512 << 10) + ((size_t)16 << 20));  // 8 MB
    u16* xb   = (u16*)(ws + (512 << 10) + ((size_t)24 << 20));  // 8 MB (reused as attnb)
    u16* Wqb  = (u16*)(ws + (512 << 10) + ((size_t)32 << 20));  // 2 MB  -- Wq/Wk/Wv contiguous
    u16* Wkb  = (u16*)(ws + (512 << 10) + ((size_t)34 << 20));
    u16* Wvb  = (u16*)(ws + (512 << 10) + ((size_t)36 << 20));
    u16* Wob  = (u16*)(ws + (512 << 10) + ((size_t)38 << 20));  // total 40.5 MB
    u16* attnb = xb;   // x no longer needed once QKV GEMM is done (stream-ordered)

    rope_tables_kernel<<<256, 256, 0, stream>>>(cost, sint);
    cvt_kernel<<<2048, 256, 0, stream>>>(x, xb);
    cvtw_kernel<<<dim3(512, 4), 256, 0, stream>>>(Wq, Wk, Wv, Wo, Wqb, Wkb, Wvb, Wob);

    gemm_qkv<<<dim3(32, 24), 256, 0, stream>>>(xb, Wqb, Qb, Kb, VT, tpos, cost, sint);

    attn_kernel<<<512, 256, 0, stream>>>(Qb, Kb, VT, attnb);

    gemm_out<<<dim3(32, 8), 256, 0, stream>>>(attnb, Wob, out);
}

// Round 8
// 148.722 us; speedup vs baseline: 3.0781x; 1.0449x over previous
//
#include <hip/hip_runtime.h>
#include <hip/hip_bf16.h>
#include <math.h>

#define D_MODEL 1024
#define NH      16
#define DK      64
#define SEQ     2048
#define BATCH   2

typedef float  f32x4  __attribute__((ext_vector_type(4)));
typedef __bf16 bf16x8 __attribute__((ext_vector_type(8)));
typedef unsigned short ushx4 __attribute__((ext_vector_type(4)));
typedef unsigned short ushx8 __attribute__((ext_vector_type(8)));
typedef unsigned short u16;

// RNE float->bf16 via compiler cast (single v_cvt on gfx950)
__device__ inline u16 cbf(float f) { __bf16 h = (__bf16)f; return *(u16*)&h; }

__device__ inline void gload16(const u16* g, u16* l) {
    // direct global->LDS DMA, 16B/lane, dest = wave-uniform base + lane*16
    __builtin_amdgcn_global_load_lds(
        (const __attribute__((address_space(1))) unsigned int*)g,
        (__attribute__((address_space(3))) unsigned int*)l,
        16, 0, 0);
}

// ---------------- RoPE tables: cos/sin [SEQ][DK/2] ----------------
__global__ void rope_tables_kernel(float* __restrict__ cost, float* __restrict__ sint) {
    int i = blockIdx.x * 256 + threadIdx.x;      // 2048*32 = 65536 total
    int pos = i >> 5, k = i & 31;
    float inv = powf(10000.0f, -2.0f * (float)k / 64.0f);
    float ang = (float)pos * inv;
    cost[i] = cosf(ang);
    sint[i] = sinf(ang);
}

// ---------------- fp32 -> bf16 converts ----------------
__global__ void cvt_kernel(const float* __restrict__ in, u16* __restrict__ out) {
    size_t i = ((size_t)blockIdx.x * 256 + threadIdx.x) * 8;
    f32x4 v0 = *(const f32x4*)(in + i);
    f32x4 v1 = *(const f32x4*)(in + i + 4);
    ushx4 o0, o1;
    #pragma unroll
    for (int e = 0; e < 4; e++) { o0[e] = cbf(v0[e]); o1[e] = cbf(v1[e]); }
    *(ushx4*)(out + i) = o0;
    *(ushx4*)(out + i + 4) = o1;
}

__global__ void cvtw_kernel(const float* __restrict__ wq, const float* __restrict__ wk,
                            const float* __restrict__ wv, const float* __restrict__ wo,
                            u16* __restrict__ oq, u16* __restrict__ ok,
                            u16* __restrict__ ov, u16* __restrict__ oo) {
    const float* in; u16* out;
    switch (blockIdx.y) {
        case 0: in = wq; out = oq; break;
        case 1: in = wk; out = ok; break;
        case 2: in = wv; out = ov; break;
        default: in = wo; out = oo; break;
    }
    size_t i = ((size_t)blockIdx.x * 256 + threadIdx.x) * 8;
    f32x4 v0 = *(const f32x4*)(in + i);
    f32x4 v1 = *(const f32x4*)(in + i + 4);
    ushx4 o0, o1;
    #pragma unroll
    for (int e = 0; e < 4; e++) { o0[e] = cbf(v0[e]); o1[e] = cbf(v1[e]); }
    *(ushx4*)(out + i) = o0;
    *(ushx4*)(out + i + 4) = o1;
}

// ---------------- fused QKV GEMM, BK=64: [4096 x 3072] = xb * Wqkv^T ----------------
// n0 < 1024: RoPE -> Qb (pre-scaled by 0.125*log2e); n0 < 2048: RoPE -> Kb; else V^T -> VT
__global__ __launch_bounds__(256) void gemm_qkv(
    const u16* __restrict__ A, const u16* __restrict__ Wqkv,
    u16* __restrict__ Qo, u16* __restrict__ Ko, u16* __restrict__ Vo,
    const int* __restrict__ tpos,
    const float* __restrict__ cost, const float* __restrict__ sint)
{
    constexpr int K = 1024;
    __shared__ u16 As[128 * 64];
    __shared__ u16 Bs[128 * 64];

    const int t  = threadIdx.x;
    const int m0 = blockIdx.x * 128, n0 = blockIdx.y * 128;
    const int lane = t & 63, wid = t >> 6;
    const int wm = wid >> 1, wn = wid & 1;
    const int lr = lane & 15, lg = lane >> 4;
    const int sr = lane >> 3, sc = lane & 7;

    // staging: wave stages rows [wid*32, wid*32+32) of both tiles, 4 gloads each.
    // LDS linear; source chunk pre-swizzled by row&7 (3-bit XOR, rule 21).
    const u16* Asrc[4]; const u16* Bsrc[4];
    #pragma unroll
    for (int i = 0; i < 4; i++) {
        int row = wid * 32 + i * 8 + sr;
        Asrc[i] = A    + (size_t)(m0 + row) * K + ((sc ^ sr) << 3);
        Bsrc[i] = Wqkv + (size_t)(n0 + row) * K + ((sc ^ sr) << 3);
    }

    f32x4 acc[4][4];
    #pragma unroll
    for (int i = 0; i < 4; i++)
        #pragma unroll
        for (int j2 = 0; j2 < 4; j2++) acc[i][j2] = 0.0f;

    for (int k0 = 0; k0 < K; k0 += 64) {
        __syncthreads();
        #pragma unroll
        for (int i = 0; i < 4; i++) gload16(Asrc[i] + k0, &As[(wid * 32 + i * 8) * 64]);
        #pragma unroll
        for (int i = 0; i < 4; i++) gload16(Bsrc[i] + k0, &Bs[(wid * 32 + i * 8) * 64]);
        __syncthreads();

        #pragma unroll
        for (int s = 0; s < 2; s++) {
            bf16x8 af[4], bfr[4];
            #pragma unroll
            for (int mi = 0; mi < 4; mi++) {
                int row = wm * 64 + mi * 16 + lr;
                af[mi] = *(const bf16x8*)&As[row * 64 + (((s * 4 + lg) ^ (lr & 7)) << 3)];
            }
            #pragma unroll
            for (int ni = 0; ni < 4; ni++) {
                int row = wn * 64 + ni * 16 + lr;
                bfr[ni] = *(const bf16x8*)&Bs[row * 64 + (((s * 4 + lg) ^ (lr & 7)) << 3)];
            }
            #pragma unroll
            for (int mi = 0; mi < 4; mi++)
                #pragma unroll
                for (int ni = 0; ni < 4; ni++)
                    acc[mi][ni] = __builtin_amdgcn_mfma_f32_16x16x32_bf16(af[mi], bfr[ni], acc[mi][ni], 0, 0, 0);
        }
    }

    const int sel = n0 >> 10;   // 0=Q, 1=K, 2=V (block-uniform)
    #pragma unroll
    for (int mi = 0; mi < 4; mi++)
        #pragma unroll
        for (int ni = 0; ni < 4; ni++) {
            f32x4 v4 = acc[mi][ni];
            #pragma unroll
            for (int r = 0; r < 4; r++) {
                int m = m0 + wm * 64 + mi * 16 + lg * 4 + r;
                int n = n0 + wn * 64 + ni * 16 + lr;
                float v = v4[r];
                int b = m >> 11, s = m & 2047;
                int h = (n >> 6) & 15, d = n & 63;
                if (sel == 2) {
                    Vo[(((size_t)b * NH + h) * DK + d) * SEQ + s] = cbf(v);
                } else {
                    float vp = __shfl_xor(v, 1);   // pair partner (n parity == lane parity)
                    int tp = tpos[s];
                    float c  = cost[tp * 32 + (d >> 1)];
                    float sn = sint[tp * 32 + (d >> 1)];
                    float res = (d & 1) ? (vp * sn + v * c) : (v * c - vp * sn);
                    if (sel == 0) res *= 0.18033688f;   // 0.125 * log2(e): softmax uses exp2
                    u16* outp = sel ? Ko : Qo;
                    outp[(((size_t)b * NH + h) * SEQ + s) * DK + d] = cbf(res);
                }
            }
        }
}

// ---------------- output projection GEMM, BK=64: fp32 out ----------------
__global__ __launch_bounds__(256) void gemm_out(
    const u16* __restrict__ A, const u16* __restrict__ W, float* __restrict__ outp)
{
    constexpr int K = 1024;
    __shared__ u16 As[128 * 64];
    __shared__ u16 Bs[128 * 64];

    const int t  = threadIdx.x;
    const int m0 = blockIdx.x * 128, n0 = blockIdx.y * 128;
    const int lane = t & 63, wid = t >> 6;
    const int wm = wid >> 1, wn = wid & 1;
    const int lr = lane & 15, lg = lane >> 4;
    const int sr = lane >> 3, sc = lane & 7;

    const u16* Asrc[4]; const u16* Bsrc[4];
    #pragma unroll
    for (int i = 0; i < 4; i++) {
        int row = wid * 32 + i * 8 + sr;
        Asrc[i] = A + (size_t)(m0 + row) * K + ((sc ^ sr) << 3);
        Bsrc[i] = W + (size_t)(n0 + row) * K + ((sc ^ sr) << 3);
    }

    f32x4 acc[4][4];
    #pragma unroll
    for (int i = 0; i < 4; i++)
        #pragma unroll
        for (int j2 = 0; j2 < 4; j2++) acc[i][j2] = 0.0f;

    for (int k0 = 0; k0 < K; k0 += 64) {
        __syncthreads();
        #pragma unroll
        for (int i = 0; i < 4; i++) gload16(Asrc[i] + k0, &As[(wid * 32 + i * 8) * 64]);
        #pragma unroll
        for (int i = 0; i < 4; i++) gload16(Bsrc[i] + k0, &Bs[(wid * 32 + i * 8) * 64]);
        __syncthreads();

        #pragma unroll
        for (int s = 0; s < 2; s++) {
            bf16x8 af[4], bfr[4];
            #pragma unroll
            for (int mi = 0; mi < 4; mi++) {
                int row = wm * 64 + mi * 16 + lr;
                af[mi] = *(const bf16x8*)&As[row * 64 + (((s * 4 + lg) ^ (lr & 7)) << 3)];
            }
            #pragma unroll
            for (int ni = 0; ni < 4; ni++) {
                int row = wn * 64 + ni * 16 + lr;
                bfr[ni] = *(const bf16x8*)&Bs[row * 64 + (((s * 4 + lg) ^ (lr & 7)) << 3)];
            }
            #pragma unroll
            for (int mi = 0; mi < 4; mi++)
                #pragma unroll
                for (int ni = 0; ni < 4; ni++)
                    acc[mi][ni] = __builtin_amdgcn_mfma_f32_16x16x32_bf16(af[mi], bfr[ni], acc[mi][ni], 0, 0, 0);
        }
    }

    #pragma unroll
    for (int mi = 0; mi < 4; mi++)
        #pragma unroll
        for (int ni = 0; ni < 4; ni++) {
            f32x4 v4 = acc[mi][ni];
            #pragma unroll
            for (int r = 0; r < 4; r++) {
                int m = m0 + wm * 64 + mi * 16 + lg * 4 + r;
                int n = n0 + wn * 64 + ni * 16 + lr;
                outp[(size_t)m * D_MODEL + n] = v4[r];
            }
        }
}

// ---------------- causal flash attention, QBLK=64 (4 blocks/CU) ----------------
// Q bf16 [b][h][s][dk] PRE-SCALED by 0.125*log2e; K bf16 [b][h][s][dk]; VT bf16 [b][h][dk][s].
// Block = 64 q-rows of one (b,h); wave w owns rows qw..qw+15. Grid 1024 = 32 qb x 32 bh.
// Swapped softmax: S^T = mfma(K, Q); O^T = mfma(V^T, P^T).
// K double-buffered, V single-buffered (32 KB LDS). Raw s_barrier + counted vmcnt:
// stage V[kt], K[kt+1] after the barrier; vmcnt(4) before K reads, vmcnt(2) before V reads.
__global__ __launch_bounds__(256) void attn_kernel(
    const u16* __restrict__ Q,
    const u16* __restrict__ Km,
    const u16* __restrict__ VT,
    u16* __restrict__ aout)
{
    __shared__ u16 Ks[2][64 * 64];   // [key][dk], 16B chunks XOR-swizzled by (key&7)
    __shared__ u16 Vs[64 * 64];      // [dk][key], 16B chunks XOR-swizzled by (dk&7)
    __shared__ u16 Pl[4][16 * 64];   // per-wave P [qrow][key], 8B chunks XOR-swizzled
    const int t = threadIdx.x, wid = t >> 6, lane = t & 63;
    const int lr = lane & 15, lg = lane >> 4;
    const int bx = blockIdx.x;
    const int j = bx & 31;
    const int qb = 31 - (bx >> 5);                    // descending work: tail = tiny blocks
    const int bh = (j & 7) * 4 + (j >> 3);            // 4 heads per XCD
    const int b = bh >> 4, h = bh & 15;
    const int q0 = qb * 64;
    const int qw = q0 + wid * 16;
    const int nkt = qb + 1;
    const int srow = lane >> 3, schunk = lane & 7;

    const u16* Qg = Q  + (size_t)bh * SEQ * DK;
    const u16* Kg = Km + (size_t)bh * SEQ * DK;
    const u16* Vg = VT + (size_t)bh * DK * SEQ;
    u16* Plw = Pl[wid];

    // Q fragments (B-operand): lane holds col qrow = qw+lr, k-elems dk = h2*32+lg*8..+7
    bf16x8 aq[2];
    #pragma unroll
    for (int h2 = 0; h2 < 2; h2++)
        aq[h2] = *(const bf16x8*)&Qg[(qw + lr) * DK + h2 * 32 + lg * 8];

    float m_run = -__builtin_inff(), l_run = 0.0f;
    f32x4 acc[4];   // acc[dg]: O[qrow=qw+lr][d = dg*16+lg*4+r]
    #pragma unroll
    for (int dg = 0; dg < 4; dg++) acc[dg] = 0.0f;

    auto stageK = [&](int buf, int kb) {              // 2 gloads per wave
        const int row0 = wid * 16;
        const u16* ks = Kg + (size_t)(kb + row0 + srow) * DK + ((schunk ^ srow) << 3);
        gload16(ks,          &Ks[buf][row0 * 64]);
        gload16(ks + 8 * DK, &Ks[buf][(row0 + 8) * 64]);
    };
    auto stageV = [&](int kb) {                       // 2 gloads per wave
        const int row0 = wid * 16;
        const u16* vs = Vg + (size_t)(row0 + srow) * SEQ + kb + ((schunk ^ srow) << 3);
        gload16(vs,                   &Vs[row0 * 64]);
        gload16(vs + (size_t)8 * SEQ, &Vs[(row0 + 8) * 64]);
    };

    stageK(0, 0);
    for (int kt = 0; kt < nkt; kt++) {
        __builtin_amdgcn_sched_barrier(0);
        __builtin_amdgcn_s_barrier();                 // raw: no vmcnt drain
        __builtin_amdgcn_sched_barrier(0);
        stageV(kt * 64);                              // V[kt] (consumed late this iter)
        stageK((kt + 1) & 1, (kt + 1 < nkt) ? (kt + 1) * 64 : 0);  // K[kt+1] (redundant on last)
        const int kb = kt * 64;

        asm volatile("s_waitcnt vmcnt(4)" ::: "memory");   // K[kt] landed (V[kt],K[kt+1] fly)
        __builtin_amdgcn_sched_barrier(0);
        // K fragments (A-operand): lane holds row key = kg*16+lr
        bf16x8 kf[4][2];
        #pragma unroll
        for (int kg = 0; kg < 4; kg++)
            #pragma unroll
            for (int h2 = 0; h2 < 2; h2++) {
                int row = kg * 16 + lr;
                kf[kg][h2] = *(const bf16x8*)&Ks[kt & 1][row * 64 + (((h2 * 4 + lg) ^ (lr & 7)) << 3)];
            }

        // S^T[key][qrow] = K . Q^T  (lane: qrow = lr, key = kg*16+lg*4+r)
        f32x4 sf[4];
        #pragma unroll
        for (int kg = 0; kg < 4; kg++) sf[kg] = 0.0f;
        __builtin_amdgcn_s_setprio(1);
        #pragma unroll
        for (int kg = 0; kg < 4; kg++) {
            sf[kg] = __builtin_amdgcn_mfma_f32_16x16x32_bf16(kf[kg][0], aq[0], sf[kg], 0, 0, 0);
            sf[kg] = __builtin_amdgcn_mfma_f32_16x16x32_bf16(kf[kg][1], aq[1], sf[kg], 0, 0, 0);
        }
        __builtin_amdgcn_s_setprio(0);

        {
            if (kb + 64 > qw) {                       // diagonal band: mask
                const int qq = qw + lr;
                #pragma unroll
                for (int kg = 0; kg < 4; kg++)
                    #pragma unroll
                    for (int r = 0; r < 4; r++)
                        if (kb + kg * 16 + lg * 4 + r > qq) sf[kg][r] = -__builtin_inff();
            }
            float cmax = sf[0][0];
            #pragma unroll
            for (int kg = 0; kg < 4; kg++)
                #pragma unroll
                for (int r = 0; r < 4; r++) cmax = fmaxf(cmax, sf[kg][r]);
            if (!__all(cmax <= m_run + 8.0f)) {       // defer-max (log2 units)
                float mt = fmaxf(cmax, __shfl_xor(cmax, 16));
                mt = fmaxf(mt, __shfl_xor(mt, 32));
                float mn = fmaxf(m_run, mt);
                float scr = exp2f(m_run - mn);
                m_run = mn;
                l_run *= scr;
                #pragma unroll
                for (int dg = 0; dg < 4; dg++) acc[dg] *= scr;
            }
            float l = 0.0f;
            const int prow = lr * 64;
            #pragma unroll
            for (int kg = 0; kg < 4; kg++) {
                ushx4 pk;
                #pragma unroll
                for (int r = 0; r < 4; r++) {
                    float p = exp2f(sf[kg][r] - m_run);
                    l += p;
                    pk[r] = cbf(p);
                }
                *(ushx4*)&Plw[prow + (((kg * 4 + lg) ^ ((lr & 7) << 1)) << 2)] = pk;
            }
            l_run += l;                               // per-lane partial (this lane's 16 keys)
        }

        asm volatile("s_waitcnt vmcnt(2)" ::: "memory");   // V[kt] landed (K[kt+1] flies)
        __builtin_amdgcn_sched_barrier(0);
        // V^T fragments (A-operand): lane holds row d = dg*16+lr, k-elems key = ck*32+lg*8..+7
        bf16x8 vf[2][4];
        #pragma unroll
        for (int ck = 0; ck < 2; ck++)
            #pragma unroll
            for (int dg = 0; dg < 4; dg++) {
                int row = dg * 16 + lr;
                vf[ck][dg] = *(const bf16x8*)&Vs[row * 64 + (((ck * 4 + lg) ^ (lr & 7)) << 3)];
            }

        asm volatile("s_waitcnt lgkmcnt(0)" ::: "memory");   // P writes done (same-wave DS order)
        __builtin_amdgcn_sched_barrier(0);
        // P^T fragments (B-operand): lane holds col qrow = lr, k-elems key = ck*32+lg*8..+7
        bf16x8 pa[2];
        #pragma unroll
        for (int ck = 0; ck < 2; ck++)
            pa[ck] = *(const bf16x8*)&Plw[lr * 64 + (((ck * 8 + lg * 2) ^ ((lr & 7) << 1)) << 2)];
        __builtin_amdgcn_s_setprio(1);
        #pragma unroll
        for (int ck = 0; ck < 2; ck++)
            #pragma unroll
            for (int dg = 0; dg < 4; dg++)
                acc[dg] = __builtin_amdgcn_mfma_f32_16x16x32_bf16(vf[ck][dg], pa[ck], acc[dg], 0, 0, 0);
        __builtin_amdgcn_s_setprio(0);
    }

    // l partials: sum across the 4 lg lane-groups of each row
    l_run += __shfl_xor(l_run, 16);
    l_run += __shfl_xor(l_run, 32);

    {
        float inv = 1.0f / l_run;
        int q = qw + lr;
        #pragma unroll
        for (int dg = 0; dg < 4; dg++) {
            ushx4 ow;
            #pragma unroll
            for (int r = 0; r < 4; r++) ow[r] = cbf(acc[dg][r] * inv);
            *(ushx4*)&aout[((size_t)b * SEQ + q) * D_MODEL + h * DK + dg * 16 + lg * 4] = ow;
        }
    }
}

extern "C" void kernel_launch(void* const* d_in, const int* in_sizes, int n_in,
                              void* d_out, int out_size, void* d_ws, size_t ws_size,
                              hipStream_t stream) {
    const float* x    = (const float*)d_in[0];
    const int*   tpos = (const int*)d_in[1];
    const float* Wq   = (const float*)d_in[2];
    const float* Wk   = (const float*)d_in[3];
    const float* Wv   = (const float*)d_in[4];
    const float* Wo   = (const float*)d_in[5];
    float* out = (float*)d_out;

    char* ws = (char*)d_ws;
    float* cost = (float*)ws;                                   // 256 KB
    float* sint = (float*)(ws + (256 << 10));                   // 256 KB
    u16* Qb   = (u16*)(ws + (512 << 10));                       // 8 MB
    u16* Kb   = (u16*)(ws + (512 << 10) + ((size_t)8  << 20));  // 8 MB
    u16* VT   = (u16*)(ws + (512 << 10) + ((size_t)16 << 20));  // 8 MB
    u16* xb   = (u16*)(ws + (512 << 10) + ((size_t)24 << 20));  // 8 MB (reused as attnb)
    u16* Wqb  = (u16*)(ws + (512 << 10) + ((size_t)32 << 20));  // 2 MB  -- Wq/Wk/Wv contiguous
    u16* Wkb  = (u16*)(ws + (512 << 10) + ((size_t)34 << 20));
    u16* Wvb  = (u16*)(ws + (512 << 10) + ((size_t)36 << 20));
    u16* Wob  = (u16*)(ws + (512 << 10) + ((size_t)38 << 20));  // total 40.5 MB
    u16* attnb = xb;   // x no longer needed once QKV GEMM is done (stream-ordered)

    rope_tables_kernel<<<256, 256, 0, stream>>>(cost, sint);
    cvt_kernel<<<2048, 256, 0, stream>>>(x, xb);
    cvtw_kernel<<<dim3(512, 4), 256, 0, stream>>>(Wq, Wk, Wv, Wo, Wqb, Wkb, Wvb, Wob);

    gemm_qkv<<<dim3(32, 24), 256, 0, stream>>>(xb, Wqb, Qb, Kb, VT, tpos, cost, sint);

    attn_kernel<<<1024, 256, 0, stream>>>(Qb, Kb, VT, attnb);

    gemm_out<<<dim3(32, 8), 256, 0, stream>>>(attnb, Wob, out);
}

// Round 9
// 131.139 us; speedup vs baseline: 3.4908x; 1.1341x over previous
//
#include <hip/hip_runtime.h>
#include <hip/hip_bf16.h>
#include <math.h>

#define D_MODEL 1024
#define NH      16
#define DK      64
#define SEQ     2048
#define BATCH   2

typedef float  f32x4  __attribute__((ext_vector_type(4)));
typedef __bf16 bf16x8 __attribute__((ext_vector_type(8)));
typedef unsigned short ushx4 __attribute__((ext_vector_type(4)));
typedef unsigned short ushx8 __attribute__((ext_vector_type(8)));
typedef unsigned short u16;

// RNE float->bf16 via compiler cast (single v_cvt on gfx950)
__device__ inline u16 cbf(float f) { __bf16 h = (__bf16)f; return *(u16*)&h; }

__device__ inline void gload16(const u16* g, u16* l) {
    // direct global->LDS DMA, 16B/lane, dest = wave-uniform base + lane*16
    __builtin_amdgcn_global_load_lds(
        (const __attribute__((address_space(1))) unsigned int*)g,
        (__attribute__((address_space(3))) unsigned int*)l,
        16, 0, 0);
}

// ---------------- RoPE tables: interleaved (cos,sin) [SEQ][DK/2] ----------------
__global__ void rope_tables_kernel(float2* __restrict__ cs) {
    int i = blockIdx.x * 256 + threadIdx.x;      // 2048*32 = 65536 total
    int pos = i >> 5, k = i & 31;
    float inv = powf(10000.0f, -2.0f * (float)k / 64.0f);
    float ang = (float)pos * inv;
    cs[i] = make_float2(cosf(ang), sinf(ang));
}

// ---------------- fp32 -> bf16 converts ----------------
__global__ void cvt_kernel(const float* __restrict__ in, u16* __restrict__ out) {
    size_t i = ((size_t)blockIdx.x * 256 + threadIdx.x) * 8;
    f32x4 v0 = *(const f32x4*)(in + i);
    f32x4 v1 = *(const f32x4*)(in + i + 4);
    ushx4 o0, o1;
    #pragma unroll
    for (int e = 0; e < 4; e++) { o0[e] = cbf(v0[e]); o1[e] = cbf(v1[e]); }
    *(ushx4*)(out + i) = o0;
    *(ushx4*)(out + i + 4) = o1;
}

__global__ void cvtw_kernel(const float* __restrict__ wq, const float* __restrict__ wk,
                            const float* __restrict__ wv, const float* __restrict__ wo,
                            u16* __restrict__ oq, u16* __restrict__ ok,
                            u16* __restrict__ ov, u16* __restrict__ oo) {
    const float* in; u16* out;
    switch (blockIdx.y) {
        case 0: in = wq; out = oq; break;
        case 1: in = wk; out = ok; break;
        case 2: in = wv; out = ov; break;
        default: in = wo; out = oo; break;
    }
    size_t i = ((size_t)blockIdx.x * 256 + threadIdx.x) * 8;
    f32x4 v0 = *(const f32x4*)(in + i);
    f32x4 v1 = *(const f32x4*)(in + i + 4);
    ushx4 o0, o1;
    #pragma unroll
    for (int e = 0; e < 4; e++) { o0[e] = cbf(v0[e]); o1[e] = cbf(v1[e]); }
    *(ushx4*)(out + i) = o0;
    *(ushx4*)(out + i + 4) = o1;
}

// ---------------- GEMM C[m][n] = sum_k A[m][k] W[n][k], 2-phase dbuf (T3-minimum) ----------------
// MODE 0: n in [0,2048): RoPE epilogue -> Qo (pre-scaled 0.125*log2e) / Ko, bf16 [b][h][s][dk]
// MODE 2: fp32 out [m][n]
// MODE 3: swapped operands (rows=n, cols=m) -> coalesced V^T store, bf16 [b][h][dk][s]
template<int MODE>
__global__ __launch_bounds__(256) void gemm_bt(
    const u16* __restrict__ A, const u16* __restrict__ W,
    u16* __restrict__ Qo, u16* __restrict__ Ko, void* __restrict__ Oo,
    const int* __restrict__ tpos, const float2* __restrict__ cs)
{
    constexpr int K = 1024;
    __shared__ u16 As[2][128 * 32];
    __shared__ u16 Bs[2][128 * 32];

    const int t  = threadIdx.x;
    const int m0 = blockIdx.x * 128, n0 = blockIdx.y * 128;
    const int lane = t & 63, wid = t >> 6;
    const int wm = wid >> 1, wn = wid & 1;       // 2x2 wave grid, 64x64 per wave
    const int lr = lane & 15, lg = lane >> 4;

    // staging: wave stages rows [wid*32, wid*32+32) of both tiles, 2 gloads each (16 rows/gload).
    // LDS linear; source chunk pre-swizzled by (row>>1)&3 (rule 21; proven r5-r7).
    const int ldrow0 = wid * 32 + (lane >> 2);
    const int ldrow1 = ldrow0 + 16;
    const int lc = lane & 3;
    const u16* Asrc0 = A + (size_t)(m0 + ldrow0) * K + ((lc ^ ((ldrow0 >> 1) & 3)) << 3);
    const u16* Asrc1 = A + (size_t)(m0 + ldrow1) * K + ((lc ^ ((ldrow1 >> 1) & 3)) << 3);
    const u16* Bsrc0 = W + (size_t)(n0 + ldrow0) * K + ((lc ^ ((ldrow0 >> 1) & 3)) << 3);
    const u16* Bsrc1 = W + (size_t)(n0 + ldrow1) * K + ((lc ^ ((ldrow1 >> 1) & 3)) << 3);
    const int d0 = (wid * 32) * 32, d1 = (wid * 32 + 16) * 32;

    f32x4 acc[4][4];
    #pragma unroll
    for (int i = 0; i < 4; i++)
        #pragma unroll
        for (int j2 = 0; j2 < 4; j2++) acc[i][j2] = 0.0f;

    auto stage = [&](int buf, int k0) {
        gload16(Asrc0 + k0, &As[buf][d0]);
        gload16(Asrc1 + k0, &As[buf][d1]);
        gload16(Bsrc0 + k0, &Bs[buf][d0]);
        gload16(Bsrc1 + k0, &Bs[buf][d1]);
    };

    stage(0, 0);
    int buf = 0;
    for (int k0 = 0; k0 < K; k0 += 32) {
        __syncthreads();                 // drains my stage gloads (vmcnt 0) + all waves' prev reads
        if (k0 + 32 < K) stage(buf ^ 1, k0 + 32);   // prefetch next tile; latency hidden by compute

        bf16x8 af[4], bfr[4];
        #pragma unroll
        for (int mi = 0; mi < 4; mi++) {
            int row = wm * 64 + mi * 16 + lr;
            af[mi] = *(const bf16x8*)&As[buf][row * 32 + ((lg ^ ((row >> 1) & 3)) << 3)];
        }
        #pragma unroll
        for (int ni = 0; ni < 4; ni++) {
            int row = wn * 64 + ni * 16 + lr;
            bfr[ni] = *(const bf16x8*)&Bs[buf][row * 32 + ((lg ^ ((row >> 1) & 3)) << 3)];
        }
        #pragma unroll
        for (int mi = 0; mi < 4; mi++)
            #pragma unroll
            for (int ni = 0; ni < 4; ni++) {
                if constexpr (MODE == 3)
                    acc[mi][ni] = __builtin_amdgcn_mfma_f32_16x16x32_bf16(bfr[ni], af[mi], acc[mi][ni], 0, 0, 0);
                else
                    acc[mi][ni] = __builtin_amdgcn_mfma_f32_16x16x32_bf16(af[mi], bfr[ni], acc[mi][ni], 0, 0, 0);
            }
        buf ^= 1;
    }

    #pragma unroll
    for (int mi = 0; mi < 4; mi++)
        #pragma unroll
        for (int ni = 0; ni < 4; ni++) {
            f32x4 v4 = acc[mi][ni];
            #pragma unroll
            for (int r = 0; r < 4; r++) {
                float v = v4[r];
                if constexpr (MODE == 3) {
                    // rows = n (head dim), cols = m (seq) -> coalesced V^T store
                    int n = n0 + wn * 64 + ni * 16 + lg * 4 + r;
                    int m = m0 + wm * 64 + mi * 16 + lr;
                    int h = n >> 6, d = n & 63;
                    int b = m >> 11, s = m & 2047;
                    ((u16*)Oo)[(((size_t)b * NH + h) * DK + d) * SEQ + s] = cbf(v);
                } else {
                    int m = m0 + wm * 64 + mi * 16 + lg * 4 + r;
                    int n = n0 + wn * 64 + ni * 16 + lr;
                    if constexpr (MODE == 2) {
                        ((float*)Oo)[(size_t)m * D_MODEL + n] = v;
                    } else {
                        int b = m >> 11, s = m & 2047;
                        int h = (n >> 6) & 15, d = n & 63;
                        float vp = __shfl_xor(v, 1);   // pair partner (n parity == lane parity)
                        int tp = tpos[s];
                        float2 c2 = cs[tp * 32 + (d >> 1)];
                        float res = (d & 1) ? (vp * c2.y + v * c2.x) : (v * c2.x - vp * c2.y);
                        const int sel = n0 >> 10;      // 0=Q (scaled), 1=K
                        if (sel == 0) res *= 0.18033688f;   // 0.125 * log2(e): softmax uses exp2
                        u16* outp = sel ? Ko : Qo;
                        outp[(((size_t)b * NH + h) * SEQ + s) * DK + d] = cbf(res);
                    }
                }
            }
        }
}

// ---------------- causal flash attention, QBLK=64 (unchanged from round 8) ----------------
__global__ __launch_bounds__(256) void attn_kernel(
    const u16* __restrict__ Q,
    const u16* __restrict__ Km,
    const u16* __restrict__ VT,
    u16* __restrict__ aout)
{
    __shared__ u16 Ks[2][64 * 64];   // [key][dk], 16B chunks XOR-swizzled by (key&7)
    __shared__ u16 Vs[64 * 64];      // [dk][key], 16B chunks XOR-swizzled by (dk&7)
    __shared__ u16 Pl[4][16 * 64];   // per-wave P [qrow][key], 8B chunks XOR-swizzled
    const int t = threadIdx.x, wid = t >> 6, lane = t & 63;
    const int lr = lane & 15, lg = lane >> 4;
    const int bx = blockIdx.x;
    const int j = bx & 31;
    const int qb = 31 - (bx >> 5);                    // descending work: tail = tiny blocks
    const int bh = (j & 7) * 4 + (j >> 3);            // 4 heads per XCD
    const int b = bh >> 4, h = bh & 15;
    const int q0 = qb * 64;
    const int qw = q0 + wid * 16;
    const int nkt = qb + 1;
    const int srow = lane >> 3, schunk = lane & 7;

    const u16* Qg = Q  + (size_t)bh * SEQ * DK;
    const u16* Kg = Km + (size_t)bh * SEQ * DK;
    const u16* Vg = VT + (size_t)bh * DK * SEQ;
    u16* Plw = Pl[wid];

    bf16x8 aq[2];
    #pragma unroll
    for (int h2 = 0; h2 < 2; h2++)
        aq[h2] = *(const bf16x8*)&Qg[(qw + lr) * DK + h2 * 32 + lg * 8];

    float m_run = -__builtin_inff(), l_run = 0.0f;
    f32x4 acc[4];   // acc[dg]: O[qrow=qw+lr][d = dg*16+lg*4+r]
    #pragma unroll
    for (int dg = 0; dg < 4; dg++) acc[dg] = 0.0f;

    auto stageK = [&](int buf, int kb) {              // 2 gloads per wave
        const int row0 = wid * 16;
        const u16* ks = Kg + (size_t)(kb + row0 + srow) * DK + ((schunk ^ srow) << 3);
        gload16(ks,          &Ks[buf][row0 * 64]);
        gload16(ks + 8 * DK, &Ks[buf][(row0 + 8) * 64]);
    };
    auto stageV = [&](int kb) {                       // 2 gloads per wave
        const int row0 = wid * 16;
        const u16* vs = Vg + (size_t)(row0 + srow) * SEQ + kb + ((schunk ^ srow) << 3);
        gload16(vs,                   &Vs[row0 * 64]);
        gload16(vs + (size_t)8 * SEQ, &Vs[(row0 + 8) * 64]);
    };

    stageK(0, 0);
    for (int kt = 0; kt < nkt; kt++) {
        __builtin_amdgcn_sched_barrier(0);
        __builtin_amdgcn_s_barrier();                 // raw: no vmcnt drain
        __builtin_amdgcn_sched_barrier(0);
        stageV(kt * 64);                              // V[kt] (consumed late this iter)
        stageK((kt + 1) & 1, (kt + 1 < nkt) ? (kt + 1) * 64 : 0);  // K[kt+1] (redundant on last)
        const int kb = kt * 64;

        asm volatile("s_waitcnt vmcnt(4)" ::: "memory");   // K[kt] landed (V[kt],K[kt+1] fly)
        __builtin_amdgcn_sched_barrier(0);
        bf16x8 kf[4][2];
        #pragma unroll
        for (int kg = 0; kg < 4; kg++)
            #pragma unroll
            for (int h2 = 0; h2 < 2; h2++) {
                int row = kg * 16 + lr;
                kf[kg][h2] = *(const bf16x8*)&Ks[kt & 1][row * 64 + (((h2 * 4 + lg) ^ (lr & 7)) << 3)];
            }

        f32x4 sf[4];
        #pragma unroll
        for (int kg = 0; kg < 4; kg++) sf[kg] = 0.0f;
        __builtin_amdgcn_s_setprio(1);
        #pragma unroll
        for (int kg = 0; kg < 4; kg++) {
            sf[kg] = __builtin_amdgcn_mfma_f32_16x16x32_bf16(kf[kg][0], aq[0], sf[kg], 0, 0, 0);
            sf[kg] = __builtin_amdgcn_mfma_f32_16x16x32_bf16(kf[kg][1], aq[1], sf[kg], 0, 0, 0);
        }
        __builtin_amdgcn_s_setprio(0);

        {
            if (kb + 64 > qw) {                       // diagonal band: mask
                const int qq = qw + lr;
                #pragma unroll
                for (int kg = 0; kg < 4; kg++)
                    #pragma unroll
                    for (int r = 0; r < 4; r++)
                        if (kb + kg * 16 + lg * 4 + r > qq) sf[kg][r] = -__builtin_inff();
            }
            float cmax = sf[0][0];
            #pragma unroll
            for (int kg = 0; kg < 4; kg++)
                #pragma unroll
                for (int r = 0; r < 4; r++) cmax = fmaxf(cmax, sf[kg][r]);
            if (!__all(cmax <= m_run + 8.0f)) {       // defer-max (log2 units)
                float mt = fmaxf(cmax, __shfl_xor(cmax, 16));
                mt = fmaxf(mt, __shfl_xor(mt, 32));
                float mn = fmaxf(m_run, mt);
                float scr = exp2f(m_run - mn);
                m_run = mn;
                l_run *= scr;
                #pragma unroll
                for (int dg = 0; dg < 4; dg++) acc[dg] *= scr;
            }
            float l = 0.0f;
            const int prow = lr * 64;
            #pragma unroll
            for (int kg = 0; kg < 4; kg++) {
                ushx4 pk;
                #pragma unroll
                for (int r = 0; r < 4; r++) {
                    float p = exp2f(sf[kg][r] - m_run);
                    l += p;
                    pk[r] = cbf(p);
                }
                *(ushx4*)&Plw[prow + (((kg * 4 + lg) ^ ((lr & 7) << 1)) << 2)] = pk;
            }
            l_run += l;                               // per-lane partial (this lane's 16 keys)
        }

        asm volatile("s_waitcnt vmcnt(2)" ::: "memory");   // V[kt] landed (K[kt+1] flies)
        __builtin_amdgcn_sched_barrier(0);
        bf16x8 vf[2][4];
        #pragma unroll
        for (int ck = 0; ck < 2; ck++)
            #pragma unroll
            for (int dg = 0; dg < 4; dg++) {
                int row = dg * 16 + lr;
                vf[ck][dg] = *(const bf16x8*)&Vs[row * 64 + (((ck * 4 + lg) ^ (lr & 7)) << 3)];
            }

        asm volatile("s_waitcnt lgkmcnt(0)" ::: "memory");   // P writes done (same-wave DS order)
        __builtin_amdgcn_sched_barrier(0);
        bf16x8 pa[2];
        #pragma unroll
        for (int ck = 0; ck < 2; ck++)
            pa[ck] = *(const bf16x8*)&Plw[lr * 64 + (((ck * 8 + lg * 2) ^ ((lr & 7) << 1)) << 2)];
        __builtin_amdgcn_s_setprio(1);
        #pragma unroll
        for (int ck = 0; ck < 2; ck++)
            #pragma unroll
            for (int dg = 0; dg < 4; dg++)
                acc[dg] = __builtin_amdgcn_mfma_f32_16x16x32_bf16(vf[ck][dg], pa[ck], acc[dg], 0, 0, 0);
        __builtin_amdgcn_s_setprio(0);
    }

    l_run += __shfl_xor(l_run, 16);
    l_run += __shfl_xor(l_run, 32);

    {
        float inv = 1.0f / l_run;
        int q = qw + lr;
        #pragma unroll
        for (int dg = 0; dg < 4; dg++) {
            ushx4 ow;
            #pragma unroll
            for (int r = 0; r < 4; r++) ow[r] = cbf(acc[dg][r] * inv);
            *(ushx4*)&aout[((size_t)b * SEQ + q) * D_MODEL + h * DK + dg * 16 + lg * 4] = ow;
        }
    }
}

extern "C" void kernel_launch(void* const* d_in, const int* in_sizes, int n_in,
                              void* d_out, int out_size, void* d_ws, size_t ws_size,
                              hipStream_t stream) {
    const float* x    = (const float*)d_in[0];
    const int*   tpos = (const int*)d_in[1];
    const float* Wq   = (const float*)d_in[2];
    const float* Wk   = (const float*)d_in[3];
    const float* Wv   = (const float*)d_in[4];
    const float* Wo   = (const float*)d_in[5];
    float* out = (float*)d_out;

    char* ws = (char*)d_ws;
    float2* cs = (float2*)ws;                                   // 512 KB
    u16* Qb   = (u16*)(ws + (512 << 10));                       // 8 MB
    u16* Kb   = (u16*)(ws + (512 << 10) + ((size_t)8  << 20));  // 8 MB
    u16* VT   = (u16*)(ws + (512 << 10) + ((size_t)16 << 20));  // 8 MB
    u16* xb   = (u16*)(ws + (512 << 10) + ((size_t)24 << 20));  // 8 MB (reused as attnb)
    u16* Wqb  = (u16*)(ws + (512 << 10) + ((size_t)32 << 20));  // 2 MB  -- Wq/Wk contiguous
    u16* Wkb  = (u16*)(ws + (512 << 10) + ((size_t)34 << 20));
    u16* Wvb  = (u16*)(ws + (512 << 10) + ((size_t)36 << 20));
    u16* Wob  = (u16*)(ws + (512 << 10) + ((size_t)38 << 20));  // total 40.5 MB
    u16* attnb = xb;   // x no longer needed once QKV GEMMs are done (stream-ordered)

    rope_tables_kernel<<<256, 256, 0, stream>>>(cs);
    cvt_kernel<<<2048, 256, 0, stream>>>(x, xb);
    cvtw_kernel<<<dim3(512, 4), 256, 0, stream>>>(Wq, Wk, Wv, Wo, Wqb, Wkb, Wvb, Wob);

    gemm_bt<0><<<dim3(32, 16), 256, 0, stream>>>(xb, Wqb, Qb, Kb, nullptr, tpos, cs);
    gemm_bt<3><<<dim3(32, 8),  256, 0, stream>>>(xb, Wvb, nullptr, nullptr, VT, tpos, cs);

    attn_kernel<<<1024, 256, 0, stream>>>(Qb, Kb, VT, attnb);

    gemm_bt<2><<<dim3(32, 8),  256, 0, stream>>>(attnb, Wob, nullptr, nullptr, out, tpos, cs);
}